// Round 13
// baseline (614.063 us; speedup 1.0000x reference)
//
#include <hip/hip_runtime.h>

#define NVAR 1000000
#define NCON 500000
#define EPB 4096     // edges per pass-A block (45 KB LDS -> 3 blocks/CU)
#define FCAP 4480    // per-half-bucket LDS stage capacity (mean 4096, sd 64 -> +6 sigma)

// ============================================================================
// Sort front-end
// ============================================================================

__global__ __launch_bounds__(256) void kA_hist2(const int4* __restrict__ src4,
                                                const int4* __restrict__ dst4,
                                                unsigned* __restrict__ bhV,
                                                unsigned* __restrict__ bhC,
                                                int ne4, int nblk) {
    __shared__ unsigned hv[1024], hc[1024];
    int tid = threadIdx.x, b = blockIdx.x;
    for (int t = tid; t < 1024; t += 256) { hv[t] = 0; hc[t] = 0; }
    __syncthreads();
    int beg = b * (EPB / 4), end = min(ne4, beg + (EPB / 4));
    for (int i = beg + tid; i < end; i += 256) {
        int4 s = src4[i];
        int4 d = dst4[i];
        atomicAdd(&hv[s.x >> 10], 1u); atomicAdd(&hv[s.y >> 10], 1u);
        atomicAdd(&hv[s.z >> 10], 1u); atomicAdd(&hv[s.w >> 10], 1u);
        atomicAdd(&hc[d.x >> 9], 1u);  atomicAdd(&hc[d.y >> 9], 1u);
        atomicAdd(&hc[d.z >> 9], 1u);  atomicAdd(&hc[d.w >> 9], 1u);
    }
    __syncthreads();
    for (int t = tid; t < 1024; t += 256) {
        bhV[(size_t)t * nblk + b] = hv[t];
        bhC[(size_t)t * nblk + b] = hc[t];
    }
}

__global__ __launch_bounds__(256) void kA_scat(const int* __restrict__ keys,
                                               const int* __restrict__ vals,
                                               const float* __restrict__ w,
                                               const unsigned int* __restrict__ scanned,
                                               int2* __restrict__ bucketed,
                                               int ne, int shift, int nblk) {
    __shared__ unsigned int h[1024];
    __shared__ unsigned int lb[1024];
    __shared__ unsigned int gb[1024];
    __shared__ unsigned int sc[256];
    __shared__ int2 stage[EPB];
    int tid = threadIdx.x, b = blockIdx.x;
    for (int t = tid; t < 1024; t += 256) {
        h[t] = 0;
        gb[t] = scanned[(size_t)t * nblk + b];
    }
    __syncthreads();
    int beg = b * EPB, end = min(ne, beg + EPB), cnt = end - beg;
    int cnt4 = cnt >> 2;
    const int4* keys4 = (const int4*)(keys + beg);
    for (int i = tid; i < cnt4; i += 256) {
        int4 k = keys4[i];
        atomicAdd(&h[k.x >> shift], 1u);
        atomicAdd(&h[k.y >> shift], 1u);
        atomicAdd(&h[k.z >> shift], 1u);
        atomicAdd(&h[k.w >> shift], 1u);
    }
    for (int i = cnt4 * 4 + tid; i < cnt; i += 256) atomicAdd(&h[keys[beg + i] >> shift], 1u);
    __syncthreads();
    unsigned v0, v1, v2, v3;
    int q = tid * 4;
    v0 = h[q]; v1 = h[q + 1]; v2 = h[q + 2]; v3 = h[q + 3];
    sc[tid] = v0 + v1 + v2 + v3;
    __syncthreads();
    for (int dd = 1; dd < 256; dd <<= 1) {
        unsigned add = (tid >= dd) ? sc[tid - dd] : 0u;
        __syncthreads();
        sc[tid] += add;
        __syncthreads();
    }
    unsigned ex = (tid == 0) ? 0u : sc[tid - 1];
    lb[q]     = ex;
    lb[q + 1] = ex + v0;
    lb[q + 2] = ex + v0 + v1;
    lb[q + 3] = ex + v0 + v1 + v2;
    __syncthreads();
    for (int t = tid; t < 1024; t += 256) h[t] = 0;
    __syncthreads();
    unsigned mask = (1u << shift) - 1u;
    const int4* vals4 = (const int4*)(vals + beg);
    const float4* w4 = (const float4*)(w + beg);
    for (int i = tid; i < cnt4; i += 256) {
        int4 k = keys4[i];
        int4 v = vals4[i];
        float4 ww = w4[i];
        {
            unsigned bkt = (unsigned)k.x >> shift;
            unsigned r = atomicAdd(&h[bkt], 1u);
            stage[lb[bkt] + r] = make_int2(__float_as_int(ww.x),
                                           (v.x << shift) | (unsigned)(k.x & (int)mask));
        }
        {
            unsigned bkt = (unsigned)k.y >> shift;
            unsigned r = atomicAdd(&h[bkt], 1u);
            stage[lb[bkt] + r] = make_int2(__float_as_int(ww.y),
                                           (v.y << shift) | (unsigned)(k.y & (int)mask));
        }
        {
            unsigned bkt = (unsigned)k.z >> shift;
            unsigned r = atomicAdd(&h[bkt], 1u);
            stage[lb[bkt] + r] = make_int2(__float_as_int(ww.z),
                                           (v.z << shift) | (unsigned)(k.z & (int)mask));
        }
        {
            unsigned bkt = (unsigned)k.w >> shift;
            unsigned r = atomicAdd(&h[bkt], 1u);
            stage[lb[bkt] + r] = make_int2(__float_as_int(ww.w),
                                           (v.w << shift) | (unsigned)(k.w & (int)mask));
        }
    }
    for (int i = cnt4 * 4 + tid; i < cnt; i += 256) {
        int k = keys[beg + i];
        unsigned bkt = (unsigned)k >> shift;
        unsigned r = atomicAdd(&h[bkt], 1u);
        stage[lb[bkt] + r] = make_int2(__float_as_int(w[beg + i]),
                                       (vals[beg + i] << shift) | (unsigned)(k & (int)mask));
    }
    __syncthreads();
    for (int i = tid; i < cnt; i += 256) {
        unsigned bb = 0;
#pragma unroll
        for (int step = 512; step > 0; step >>= 1) {
            unsigned cand = bb + step;
            if (cand < 1024 && lb[cand] <= (unsigned)i) bb = cand;
        }
        bucketed[gb[bb] + ((unsigned)i - lb[bb])] = stage[i];
    }
}

// per-bucket low-bit histogram -> per-node degree (runtime lowbits)
__global__ __launch_bounds__(256) void kDeg(const int2* __restrict__ bucketed,
                                            const unsigned* __restrict__ scanned,
                                            unsigned* __restrict__ deg,
                                            int nnodes, int nblk, int lowbits) {
    __shared__ unsigned h[1024];
    int d = blockIdx.x, tid = threadIdx.x;
    int W = 1 << lowbits;
    unsigned mask = (unsigned)(W - 1);
    unsigned base = scanned[(size_t)d * nblk], next = scanned[(size_t)(d + 1) * nblk];
    for (int t = tid; t < W; t += 256) h[t] = 0;
    __syncthreads();
    for (unsigned i = base + tid; i < next; i += 256)
        atomicAdd(&h[(unsigned)bucketed[i].y & mask], 1u);
    __syncthreads();
    int lo = d << lowbits;
    for (int t = tid; t < W; t += 256) {
        int node = lo + t;
        if (node < nnodes) deg[node] = h[t];
    }
}

// NOTE: no __restrict__ -- used in-place (in == out) for the deg->start scans
__global__ __launch_bounds__(256) void k_scan_blocks(const unsigned int* in,
                                                     unsigned int* out,
                                                     unsigned int* bsum,
                                                     int n) {
    __shared__ unsigned int sT[256];
    int base = blockIdx.x * 1024 + threadIdx.x * 4;
    unsigned int v0 = 0, v1 = 0, v2 = 0, v3 = 0;
    if (base + 3 < n) {
        uint4 u = *(const uint4*)(in + base);
        v0 = u.x; v1 = u.y; v2 = u.z; v3 = u.w;
    } else {
        if (base     < n) v0 = in[base];
        if (base + 1 < n) v1 = in[base + 1];
        if (base + 2 < n) v2 = in[base + 2];
        if (base + 3 < n) v3 = in[base + 3];
    }
    sT[threadIdx.x] = v0 + v1 + v2 + v3;
    __syncthreads();
    for (int d = 1; d < 256; d <<= 1) {
        unsigned int add = (threadIdx.x >= (unsigned)d) ? sT[threadIdx.x - d] : 0u;
        __syncthreads();
        sT[threadIdx.x] += add;
        __syncthreads();
    }
    unsigned int excl = (threadIdx.x == 0) ? 0u : sT[threadIdx.x - 1];
    if (base     < n) out[base]     = excl;
    if (base + 1 < n) out[base + 1] = excl + v0;
    if (base + 2 < n) out[base + 2] = excl + v0 + v1;
    if (base + 3 < n) out[base + 3] = excl + v0 + v1 + v2;
    if (threadIdx.x == 255 && bsum) bsum[blockIdx.x] = sT[255];
}

// single-block looped exclusive scan (handles n > 1024, e.g. 1954 block sums)
__global__ __launch_bounds__(256) void k_scan_mid(const unsigned* __restrict__ in,
                                                  unsigned* __restrict__ out, int n) {
    __shared__ unsigned sT[256];
    __shared__ unsigned carry;
    if (threadIdx.x == 0) carry = 0;
    __syncthreads();
    for (int base = 0; base < n; base += 256) {
        int i = base + threadIdx.x;
        unsigned v = (i < n) ? in[i] : 0u;
        sT[threadIdx.x] = v;
        __syncthreads();
        for (int d = 1; d < 256; d <<= 1) {
            unsigned add = (threadIdx.x >= (unsigned)d) ? sT[threadIdx.x - d] : 0u;
            __syncthreads();
            sT[threadIdx.x] += add;
            __syncthreads();
        }
        unsigned excl = carry + ((threadIdx.x == 0) ? 0u : sT[threadIdx.x - 1]);
        if (i < n) out[i] = excl;
        __syncthreads();
        if (threadIdx.x == 255) carry += sT[255];
        __syncthreads();
    }
}

__global__ __launch_bounds__(256) void k_scan_add(unsigned int* __restrict__ data,
                                                  const unsigned int* __restrict__ bscan,
                                                  int n) {
    int base = blockIdx.x * 1024 + threadIdx.x * 4;
    unsigned int add = bscan[blockIdx.x];
    if (base + 3 < n) {
        uint4 u = *(const uint4*)(data + base);
        u.x += add; u.y += add; u.z += add; u.w += add;
        *(uint4*)(data + base) = u;
    } else {
        if (base     < n) data[base]     += add;
        if (base + 1 < n) data[base + 1] += add;
        if (base + 2 < n) data[base + 2] += add;
        if (base + 3 < n) data[base + 3] += add;
    }
}

// ============================================================================
// Node pipeline
// ============================================================================

// pack per-var (c, x, rsqrt(deg)) -> 16 B rows; conv1 computes embedding on the fly
__global__ __launch_bounds__(256) void k_pack(const float* __restrict__ var_c,
                                              const float* __restrict__ var_x,
                                              const unsigned int* __restrict__ deg_var,
                                              float4* __restrict__ vcr, int n) {
    int i = blockIdx.x * blockDim.x + threadIdx.x;
    if (i >= n) return;
    float rs = rsqrtf(fmaxf((float)deg_var[i], 1.0f));
    vcr[i] = make_float4(var_c[i], var_x[i], rs, 0.0f);
}

// embed+accumulate one staged edge: identical op order to the old Xs path
#define EMBADD(e)                                                             \
    {                                                                         \
        float4 vv = vcr[(size_t)(e).y];                                       \
        float we = __int_as_float((e).x);                                     \
        float t0 = fmaf(vv.x, wv0[0], fmaf(vv.y, wv1[0], bvr[0]));            \
        float t1 = fmaf(vv.x, wv0[1], fmaf(vv.y, wv1[1], bvr[1]));            \
        float t2 = fmaf(vv.x, wv0[2], fmaf(vv.y, wv1[2], bvr[2]));            \
        float t3 = fmaf(vv.x, wv0[3], fmaf(vv.y, wv1[3], bvr[3]));            \
        acc.x = fmaf(we, fmaxf(t0, 0.f) * vv.z, acc.x);                       \
        acc.y = fmaf(we, fmaxf(t1, 0.f) * vv.z, acc.y);                       \
        acc.z = fmaf(we, fmaxf(t2, 0.f) * vv.z, acc.z);                       \
        acc.w = fmaf(we, fmaxf(t3, 0.f) * vv.z, acc.w);                       \
    }

#define EMB4(eA, eB, eC, eD)                                                  \
    {                                                                         \
        float4 vA = vcr[(size_t)(eA).y];                                      \
        float4 vB = vcr[(size_t)(eB).y];                                      \
        float4 vC = vcr[(size_t)(eC).y];                                      \
        float4 vD = vcr[(size_t)(eD).y];                                      \
        float wA = __int_as_float((eA).x), wB = __int_as_float((eB).x);       \
        float wC = __int_as_float((eC).x), wD = __int_as_float((eD).x);       \
        float t0, t1, t2, t3;                                                 \
        t0 = fmaf(vA.x, wv0[0], fmaf(vA.y, wv1[0], bvr[0]));                  \
        t1 = fmaf(vA.x, wv0[1], fmaf(vA.y, wv1[1], bvr[1]));                  \
        t2 = fmaf(vA.x, wv0[2], fmaf(vA.y, wv1[2], bvr[2]));                  \
        t3 = fmaf(vA.x, wv0[3], fmaf(vA.y, wv1[3], bvr[3]));                  \
        acc.x = fmaf(wA, fmaxf(t0, 0.f) * vA.z, acc.x);                       \
        acc.y = fmaf(wA, fmaxf(t1, 0.f) * vA.z, acc.y);                       \
        acc.z = fmaf(wA, fmaxf(t2, 0.f) * vA.z, acc.z);                       \
        acc.w = fmaf(wA, fmaxf(t3, 0.f) * vA.z, acc.w);                       \
        t0 = fmaf(vB.x, wv0[0], fmaf(vB.y, wv1[0], bvr[0]));                  \
        t1 = fmaf(vB.x, wv0[1], fmaf(vB.y, wv1[1], bvr[1]));                  \
        t2 = fmaf(vB.x, wv0[2], fmaf(vB.y, wv1[2], bvr[2]));                  \
        t3 = fmaf(vB.x, wv0[3], fmaf(vB.y, wv1[3], bvr[3]));                  \
        acc.x = fmaf(wB, fmaxf(t0, 0.f) * vB.z, acc.x);                       \
        acc.y = fmaf(wB, fmaxf(t1, 0.f) * vB.z, acc.y);                       \
        acc.z = fmaf(wB, fmaxf(t2, 0.f) * vB.z, acc.z);                       \
        acc.w = fmaf(wB, fmaxf(t3, 0.f) * vB.z, acc.w);                       \
        t0 = fmaf(vC.x, wv0[0], fmaf(vC.y, wv1[0], bvr[0]));                  \
        t1 = fmaf(vC.x, wv0[1], fmaf(vC.y, wv1[1], bvr[1]));                  \
        t2 = fmaf(vC.x, wv0[2], fmaf(vC.y, wv1[2], bvr[2]));                  \
        t3 = fmaf(vC.x, wv0[3], fmaf(vC.y, wv1[3], bvr[3]));                  \
        acc.x = fmaf(wC, fmaxf(t0, 0.f) * vC.z, acc.x);                       \
        acc.y = fmaf(wC, fmaxf(t1, 0.f) * vC.z, acc.y);                       \
        acc.z = fmaf(wC, fmaxf(t2, 0.f) * vC.z, acc.z);                       \
        acc.w = fmaf(wC, fmaxf(t3, 0.f) * vC.z, acc.w);                       \
        t0 = fmaf(vD.x, wv0[0], fmaf(vD.y, wv1[0], bvr[0]));                  \
        t1 = fmaf(vD.x, wv0[1], fmaf(vD.y, wv1[1], bvr[1]));                  \
        t2 = fmaf(vD.x, wv0[2], fmaf(vD.y, wv1[2], bvr[2]));                  \
        t3 = fmaf(vD.x, wv0[3], fmaf(vD.y, wv1[3], bvr[3]));                  \
        acc.x = fmaf(wD, fmaxf(t0, 0.f) * vD.z, acc.x);                       \
        acc.y = fmaf(wD, fmaxf(t1, 0.f) * vD.z, acc.y);                       \
        acc.z = fmaf(wD, fmaxf(t2, 0.f) * vD.z, acc.z);                       \
        acc.w = fmaf(wD, fmaxf(t3, 0.f) * vD.z, acc.w);                       \
    }

// conv1 fused, half-bucket of 256 con nodes; on-the-fly var embedding from vcr
__global__ __launch_bounds__(512) void kF_con(const int2* __restrict__ bucketed,
                                              const unsigned* __restrict__ scanned,
                                              const unsigned* __restrict__ startC,
                                              const float4* __restrict__ vcr,
                                              const float* __restrict__ Wv,
                                              const float* __restrict__ bv,
                                              const float* __restrict__ W2,
                                              const float* __restrict__ b2,
                                              float* __restrict__ hs, int nblk, int netot) {
    __shared__ unsigned sraw[257], cr[256];
    __shared__ float sWv[20], sbv[10], sW[100], sb[10];
    __shared__ int2 stage[FCAP];
    int tid = threadIdx.x;
    int d = blockIdx.x >> 1, half = blockIdx.x & 1;
    int gbase = (d << 9) + half * 256;
    for (int t = tid; t < 100; t += 512) sW[t] = W2[t];
    if (tid < 10) sb[tid] = b2[tid];
    if (tid < 20) sWv[tid] = Wv[tid];
    if (tid >= 20 && tid < 30) sbv[tid - 20] = bv[tid - 20];
    for (int t = tid; t < 257; t += 512) {
        int g = gbase + t;
        sraw[t] = (g < NCON) ? startC[g] : (unsigned)netot;
    }
    if (tid < 256) cr[tid] = 0;
    __syncthreads();
    unsigned own_beg = sraw[0], own_end = sraw[256];
    bool fit = (int)(own_end - own_beg) <= FCAP;
    unsigned bbase = scanned[(size_t)d * nblk];
    unsigned bnext = scanned[(size_t)(d + 1) * nblk];
    int bsz = (int)(bnext - bbase);
    if (fit) {
        for (int i = tid; i < bsz; i += 512) {
            int2 p = bucketed[bbase + i];
            unsigned low = (unsigned)p.y & 511u;
            if ((int)(low >> 8) == half) {
                unsigned nl = low & 255u;
                unsigned r = atomicAdd(&cr[nl], 1u);
                stage[sraw[nl] - own_beg + r] = make_int2(p.x, p.y >> 9);
            }
        }
    }
    __syncthreads();
    int quad = tid >> 2, lane = tid & 3, c0 = lane * 4;
    float wv0[4], wv1[4], bvr[4];
#pragma unroll
    for (int k = 0; k < 4; k++) {
        int j = c0 + k;
        wv0[k] = (j < 10) ? sWv[j] : 0.f;
        wv1[k] = (j < 10) ? sWv[10 + j] : 0.f;
        bvr[k] = (j < 10) ? sbv[j] : 0.f;
    }
#pragma unroll
    for (int rr = 0; rr < 2; rr++) {
        int nl = rr * 128 + quad;
        int g = gbase + nl;
        if (g >= NCON) continue;
        float4 acc = make_float4(0.f, 0.f, 0.f, 0.f);
        unsigned cnt;
        if (fit) {
            unsigned beg = sraw[nl] - own_beg;
            cnt = cr[nl];
            unsigned end = beg + cnt, p = beg;
            for (; p + 4 <= end; p += 4) {
                int2 e0 = stage[p], e1 = stage[p + 1], e2 = stage[p + 2], e3 = stage[p + 3];
                EMB4(e0, e1, e2, e3);
            }
            for (; p < end; ++p) {
                int2 e = stage[p];
                EMBADD(e);
            }
        } else {   // statistically unreachable safety path
            cnt = 0;
            unsigned target = (unsigned)(half * 256 + nl);
            for (int i = 0; i < bsz; ++i) {
                int2 p = bucketed[bbase + i];
                if (((unsigned)p.y & 511u) == target) {
                    ++cnt;
                    int2 e = make_int2(p.x, p.y >> 9);
                    EMBADD(e);
                }
            }
        }
        float rs = rsqrtf(fmaxf((float)cnt, 1.0f));
        float a[10];
        a[0] = __shfl(acc.x, 0, 4); a[1] = __shfl(acc.y, 0, 4);
        a[2] = __shfl(acc.z, 0, 4); a[3] = __shfl(acc.w, 0, 4);
        a[4] = __shfl(acc.x, 1, 4); a[5] = __shfl(acc.y, 1, 4);
        a[6] = __shfl(acc.z, 1, 4); a[7] = __shfl(acc.w, 1, 4);
        a[8] = __shfl(acc.x, 2, 4); a[9] = __shfl(acc.y, 2, 4);
#pragma unroll
        for (int j = 0; j < 10; j++) a[j] *= rs;
        float o[12];
#pragma unroll
        for (int k = 0; k < 10; k++) {
            float t = sb[k];
#pragma unroll
            for (int j = 0; j < 10; j++) t = fmaf(a[j], sW[j * 10 + k], t);
            o[k] = fmaxf(t, 0.0f) * rs;   // relu + prescale for conv2
        }
        o[10] = 0.0f; o[11] = 0.0f;
        float4 wv = (lane < 3) ? make_float4(o[c0], o[c0 + 1], o[c0 + 2], o[c0 + 3])
                               : make_float4(0.f, 0.f, 0.f, 0.f);
        *(float4*)(hs + (size_t)g * 16 + c0) = wv;
    }
}

#define GATHER4(eA, eB, eC, eD, TAB)                                          \
    {                                                                         \
        float4 v0 = *(const float4*)(TAB + (size_t)(eA).y * 16 + c0);         \
        float4 v1 = *(const float4*)(TAB + (size_t)(eB).y * 16 + c0);         \
        float4 v2 = *(const float4*)(TAB + (size_t)(eC).y * 16 + c0);         \
        float4 v3 = *(const float4*)(TAB + (size_t)(eD).y * 16 + c0);         \
        float w0 = __int_as_float((eA).x), w1 = __int_as_float((eB).x);       \
        float w2 = __int_as_float((eC).x), w3 = __int_as_float((eD).x);       \
        acc.x = fmaf(w0, v0.x, acc.x); acc.y = fmaf(w0, v0.y, acc.y);         \
        acc.z = fmaf(w0, v0.z, acc.z); acc.w = fmaf(w0, v0.w, acc.w);         \
        acc.x = fmaf(w1, v1.x, acc.x); acc.y = fmaf(w1, v1.y, acc.y);         \
        acc.z = fmaf(w1, v1.z, acc.z); acc.w = fmaf(w1, v1.w, acc.w);         \
        acc.x = fmaf(w2, v2.x, acc.x); acc.y = fmaf(w2, v2.y, acc.y);         \
        acc.z = fmaf(w2, v2.z, acc.z); acc.w = fmaf(w2, v2.w, acc.w);         \
        acc.x = fmaf(w3, v3.x, acc.x); acc.y = fmaf(w3, v3.y, acc.y);         \
        acc.z = fmaf(w3, v3.z, acc.z); acc.w = fmaf(w3, v3.w, acc.w);         \
    }

// conv2 fused, half-bucket of 512 var nodes: rank-stage, gather hs, dense + MLP,
// per-block partial mean.
__global__ __launch_bounds__(512) void kF_fin(const int2* __restrict__ bucketed,
                                              const unsigned* __restrict__ scanned,
                                              const unsigned* __restrict__ startV,
                                              const float* __restrict__ feat,
                                              const float* __restrict__ W2,
                                              const float* __restrict__ b2,
                                              const float* __restrict__ Wo1,
                                              const float* __restrict__ bo1,
                                              const float* __restrict__ Wo2,
                                              const float* __restrict__ bo2,
                                              const float* __restrict__ Wo3,
                                              const float* __restrict__ bo3,
                                              double* __restrict__ partials, int nblk, int netot) {
    __shared__ unsigned sraw[513], cr[512];
    __shared__ float sW2[100], sb2[10], sWo1[100], sbo1[10], sWo2[100], sbo2[10], sWo3[10], sbo3v;
    __shared__ int2 stage[FCAP];
    __shared__ double red[512];
    int tid = threadIdx.x;
    int d = blockIdx.x >> 1, half = blockIdx.x & 1;
    int gbase = (d << 10) + half * 512;
    for (int t = tid; t < 100; t += 512) { sW2[t] = W2[t]; sWo1[t] = Wo1[t]; sWo2[t] = Wo2[t]; }
    if (tid < 10) {
        sb2[tid] = b2[tid]; sbo1[tid] = bo1[tid]; sbo2[tid] = bo2[tid]; sWo3[tid] = Wo3[tid];
    }
    if (tid == 0) sbo3v = bo3[0];
    for (int t = tid; t < 513; t += 512) {
        int g = gbase + t;
        sraw[t] = (g < NVAR) ? startV[g] : (unsigned)netot;
    }
    cr[tid] = 0;
    __syncthreads();
    unsigned own_beg = sraw[0], own_end = sraw[512];
    bool fit = (int)(own_end - own_beg) <= FCAP;
    unsigned bbase = scanned[(size_t)d * nblk];
    unsigned bnext = scanned[(size_t)(d + 1) * nblk];
    int bsz = (int)(bnext - bbase);
    if (fit) {
        for (int i = tid; i < bsz; i += 512) {
            int2 p = bucketed[bbase + i];
            unsigned low = (unsigned)p.y & 1023u;
            if ((int)(low >> 9) == half) {
                unsigned nl = low & 511u;
                unsigned r = atomicAdd(&cr[nl], 1u);
                stage[sraw[nl] - own_beg + r] = make_int2(p.x, p.y >> 10);
            }
        }
    }
    __syncthreads();
    int quad = tid >> 2, lane = tid & 3, c0 = lane * 4;
    double accd = 0.0;
#pragma unroll
    for (int rr = 0; rr < 4; rr++) {
        int nl = rr * 128 + quad;
        int g = gbase + nl;
        if (g >= NVAR) continue;
        float4 acc = make_float4(0.f, 0.f, 0.f, 0.f);
        unsigned cnt;
        if (fit) {
            unsigned beg = sraw[nl] - own_beg;
            cnt = cr[nl];
            unsigned end = beg + cnt, p = beg;
            for (; p + 4 <= end; p += 4) {
                int2 e0 = stage[p], e1 = stage[p + 1], e2 = stage[p + 2], e3 = stage[p + 3];
                GATHER4(e0, e1, e2, e3, feat);
            }
            for (; p < end; ++p) {
                int2 e = stage[p];
                float4 v = *(const float4*)(feat + (size_t)e.y * 16 + c0);
                float we = __int_as_float(e.x);
                acc.x = fmaf(we, v.x, acc.x); acc.y = fmaf(we, v.y, acc.y);
                acc.z = fmaf(we, v.z, acc.z); acc.w = fmaf(we, v.w, acc.w);
            }
        } else {   // statistically unreachable safety path
            cnt = 0;
            unsigned target = (unsigned)(half * 512 + nl);
            for (int i = 0; i < bsz; ++i) {
                int2 p = bucketed[bbase + i];
                if (((unsigned)p.y & 1023u) == target) {
                    ++cnt;
                    float4 v = *(const float4*)(feat + (size_t)((unsigned)p.y >> 10) * 16 + c0);
                    float we = __int_as_float(p.x);
                    acc.x = fmaf(we, v.x, acc.x); acc.y = fmaf(we, v.y, acc.y);
                    acc.z = fmaf(we, v.z, acc.z); acc.w = fmaf(we, v.w, acc.w);
                }
            }
        }
        float rs = rsqrtf(fmaxf((float)cnt, 1.0f));
        float a[10];
        a[0] = __shfl(acc.x, 0, 4); a[1] = __shfl(acc.y, 0, 4);
        a[2] = __shfl(acc.z, 0, 4); a[3] = __shfl(acc.w, 0, 4);
        a[4] = __shfl(acc.x, 1, 4); a[5] = __shfl(acc.y, 1, 4);
        a[6] = __shfl(acc.z, 1, 4); a[7] = __shfl(acc.w, 1, 4);
        a[8] = __shfl(acc.x, 2, 4); a[9] = __shfl(acc.y, 2, 4);
#pragma unroll
        for (int j = 0; j < 10; j++) a[j] *= rs;
        float hh[10], z[10];
#pragma unroll
        for (int k = 0; k < 10; k++) {
            float t = sb2[k];
#pragma unroll
            for (int j = 0; j < 10; j++) t = fmaf(a[j], sW2[j * 10 + k], t);
            hh[k] = fmaxf(t, 0.0f);
        }
#pragma unroll
        for (int k = 0; k < 10; k++) {
            float t = sbo1[k];
#pragma unroll
            for (int j = 0; j < 10; j++) t = fmaf(hh[j], sWo1[j * 10 + k], t);
            z[k] = fmaxf(t, 0.0f);
        }
        float t3 = sbo3v;
#pragma unroll
        for (int k = 0; k < 10; k++) {
            float t = sbo2[k];
#pragma unroll
            for (int j = 0; j < 10; j++) t = fmaf(z[j], sWo2[j * 10 + k], t);
            t = fmaxf(t, 0.0f);
            t3 = fmaf(t, sWo3[k], t3);
        }
        if (lane == 0) accd += (double)t3;
    }
    red[tid] = accd;
    __syncthreads();
    for (int off = 256; off > 0; off >>= 1) {
        if (tid < off) red[tid] += red[tid + off];
        __syncthreads();
    }
    if (tid == 0) partials[blockIdx.x] = red[0];
}

__global__ __launch_bounds__(256) void k_out(const double* __restrict__ partials, int np,
                                             float* __restrict__ out) {
    __shared__ double red[256];
    double a = 0.0;
    for (int i = threadIdx.x; i < np; i += blockDim.x) a += partials[i];
    red[threadIdx.x] = a;
    __syncthreads();
    for (int off = 128; off > 0; off >>= 1) {
        if (threadIdx.x < off) red[threadIdx.x] += red[threadIdx.x + off];
        __syncthreads();
    }
    if (threadIdx.x == 0) out[0] = (float)(red[0] / (double)NVAR);
}

// ============================================================================
// Launch
// ============================================================================

extern "C" void kernel_launch(void* const* d_in, const int* in_sizes, int n_in,
                              void* d_out, int out_size, void* d_ws, size_t ws_size,
                              hipStream_t stream) {
    const float* var_c  = (const float*)d_in[0];
    const float* var_x  = (const float*)d_in[1];
    const int*   e_src  = (const int*)d_in[3];
    const int*   e_dst  = (const int*)d_in[4];
    const float* e_w    = (const float*)d_in[5];
    const float* Wv     = (const float*)d_in[6];
    const float* bv     = (const float*)d_in[7];
    const float* W2     = (const float*)d_in[12];
    const float* b2     = (const float*)d_in[13];
    const float* Wo1    = (const float*)d_in[14];
    const float* bo1    = (const float*)d_in[15];
    const float* Wo2    = (const float*)d_in[16];
    const float* bo2    = (const float*)d_in[17];
    const float* Wo3    = (const float*)d_in[18];
    const float* bo3    = (const float*)d_in[19];
    float* out = (float*)d_out;
    const int ne = in_sizes[3];
    (void)n_in; (void)out_size; (void)ws_size;

    const int B = 256;
    const int nblkA = (ne + EPB - 1) / EPB;       // 1954
    const int scanN = 1024 * nblkA;               // ~2.0M
    const int NBs   = (scanN + 1023) / 1024;      // 1954
    const int BKV   = (NVAR + 1023) >> 10;        // 977 (shift 10)
    const int BKC   = (NCON + 511) >> 9;          // 977 (shift 9)
    const int NBV   = (NVAR + 1023) / 1024;       // 977
    const int NBC   = (NCON + 1023) / 1024;       // 489
    const int ne4   = ne / 4;

    char* ws = (char*)d_ws;
    size_t off = 0;
    auto walloc = [&](size_t bytes) {
        void* p = ws + off;
        off = (off + bytes + 255) & ~(size_t)255;
        return p;
    };

    int2*     bucketedV = (int2*)walloc((size_t)ne * 8);           // 64 MB
    int2*     bucketedC = (int2*)walloc((size_t)ne * 8);           // 64 MB
    float4*   vcr       = (float4*)walloc((size_t)NVAR * 16);      // 16 MB
    float*    hs64      = (float*)walloc((size_t)NCON * 16 * 4);   // 32 MB
    unsigned* scannedV  = (unsigned*)walloc((size_t)scanN * 4);    //  8 MB
    unsigned* scannedC  = (unsigned*)walloc((size_t)scanN * 4);    //  8 MB
    unsigned* bhV       = (unsigned*)walloc((size_t)scanN * 4);    //  8 MB
    unsigned* bhC       = (unsigned*)walloc((size_t)scanN * 4);    //  8 MB
    unsigned* bsumA     = (unsigned*)walloc(8192);
    unsigned* bscanA    = (unsigned*)walloc(8192);
    double*   partials  = (double*)walloc((size_t)(BKV * 2) * 8 + 64);
    // overlays: bhV dead after its bucket scan -> deg_var (in-place scan -> startV)
    //           bhC dead after its bucket scan -> deg_con (in-place scan -> startC)
    unsigned* deg_var   = bhV;
    unsigned* deg_con   = bhC;

    // 1. fused dual histogram
    kA_hist2<<<nblkA, B, 0, stream>>>((const int4*)e_src, (const int4*)e_dst,
                                      bhV, bhC, ne4, nblkA);

    // 2. bucket-level scans -> global segment bases
    k_scan_blocks<<<NBs, B, 0, stream>>>(bhV, scannedV, bsumA, scanN);
    k_scan_mid   <<<1,   B, 0, stream>>>(bsumA, bscanA, NBs);
    k_scan_add   <<<NBs, B, 0, stream>>>(scannedV, bscanA, scanN);
    k_scan_blocks<<<NBs, B, 0, stream>>>(bhC, scannedC, bsumA, scanN);
    k_scan_mid   <<<1,   B, 0, stream>>>(bsumA, bscanA, NBs);
    k_scan_add   <<<NBs, B, 0, stream>>>(scannedC, bscanA, scanN);

    // 3. V-direction bucketing (key=src var, val=dst con); bhV now dead
    kA_scat<<<nblkA, B, 0, stream>>>(e_src, e_dst, e_w, scannedV, bucketedV, ne, 10, nblkA);

    // 4. per-node var degrees (overlay on bhV)
    kDeg<<<BKV, B, 0, stream>>>(bucketedV, scannedV, deg_var, NVAR, nblkA, 10);

    // 5. pack (c, x, rsqrt(deg)) -- must read deg BEFORE the in-place scan
    k_pack<<<(NVAR + B - 1) / B, B, 0, stream>>>(var_c, var_x, deg_var, vcr, NVAR);

    // 6. in-place exclusive scan deg_var -> startV
    k_scan_blocks<<<NBV, B, 0, stream>>>(deg_var, deg_var, bsumA, NVAR);
    k_scan_mid   <<<1,   B, 0, stream>>>(bsumA, bscanA, NBV);
    k_scan_add   <<<NBV, B, 0, stream>>>(deg_var, bscanA, NVAR);

    // 7. C-direction bucketing (key=dst con, val=src var); bhC now dead
    kA_scat<<<nblkA, B, 0, stream>>>(e_dst, e_src, e_w, scannedC, bucketedC, ne, 9, nblkA);

    // 8. per-node con degrees (overlay on bhC), in-place scan -> startC
    kDeg<<<BKC, B, 0, stream>>>(bucketedC, scannedC, deg_con, NCON, nblkA, 9);
    k_scan_blocks<<<NBC, B, 0, stream>>>(deg_con, deg_con, bsumA, NCON);
    k_scan_mid   <<<1,   B, 0, stream>>>(bsumA, bscanA, NBC);
    k_scan_add   <<<NBC, B, 0, stream>>>(deg_con, bscanA, NCON);

    // 9. conv1 fused (half-buckets, on-the-fly embedding from vcr)
    kF_con<<<BKC * 2, 512, 0, stream>>>(bucketedC, scannedC, deg_con, vcr, Wv, bv,
                                        W2, b2, hs64, nblkA, ne);

    // 10. conv2 fused (half-buckets) + MLP + partials
    kF_fin<<<BKV * 2, 512, 0, stream>>>(bucketedV, scannedV, deg_var, hs64, W2, b2,
                                        Wo1, bo1, Wo2, bo2, Wo3, bo3, partials, nblkA, ne);

    // 11. final mean
    k_out<<<1, B, 0, stream>>>(partials, BKV * 2, out);
}

// Round 14
// 564.287 us; speedup vs baseline: 1.0882x; 1.0882x over previous
//
#include <hip/hip_runtime.h>

#define NVAR 1000000
#define NCON 500000
#define EPB 8192     // edges per pass-A block
#define FCAP 4480    // per-half-bucket LDS stage capacity (mean 4096, sd 64 -> +6 sigma)

// ============================================================================
// Sort front-end
// ============================================================================

__global__ __launch_bounds__(256) void kA_hist2(const int4* __restrict__ src4,
                                                const int4* __restrict__ dst4,
                                                unsigned* __restrict__ bhV,
                                                unsigned* __restrict__ bhC,
                                                int ne4, int nblk) {
    __shared__ unsigned hv[1024], hc[1024];
    int tid = threadIdx.x, b = blockIdx.x;
    for (int t = tid; t < 1024; t += 256) { hv[t] = 0; hc[t] = 0; }
    __syncthreads();
    int beg = b * (EPB / 4), end = min(ne4, beg + (EPB / 4));
    for (int i = beg + tid; i < end; i += 256) {
        int4 s = src4[i];
        int4 d = dst4[i];
        atomicAdd(&hv[s.x >> 10], 1u); atomicAdd(&hv[s.y >> 10], 1u);
        atomicAdd(&hv[s.z >> 10], 1u); atomicAdd(&hv[s.w >> 10], 1u);
        atomicAdd(&hc[d.x >> 9], 1u);  atomicAdd(&hc[d.y >> 9], 1u);
        atomicAdd(&hc[d.z >> 9], 1u);  atomicAdd(&hc[d.w >> 9], 1u);
    }
    __syncthreads();
    for (int t = tid; t < 1024; t += 256) {
        bhV[(size_t)t * nblk + b] = hv[t];
        bhC[(size_t)t * nblk + b] = hc[t];
    }
}

// rank-stage payload in LDS (+ bucket id in u16 sbkt), emit slots in order.
// All global reads sequential; emit is direct (no binary search).
__global__ __launch_bounds__(256) void kA_scat(const int* __restrict__ keys,
                                               const int* __restrict__ vals,
                                               const float* __restrict__ w,
                                               const unsigned int* __restrict__ scanned,
                                               int2* __restrict__ bucketed,
                                               int ne, int shift, int nblk) {
    __shared__ unsigned int h[1024];
    __shared__ unsigned int lb[1024];
    __shared__ unsigned int gb[1024];
    __shared__ unsigned int sc[256];
    __shared__ int2 stage[EPB];
    __shared__ unsigned short sbkt[EPB];
    int tid = threadIdx.x, b = blockIdx.x;
    for (int t = tid; t < 1024; t += 256) {
        h[t] = 0;
        gb[t] = scanned[(size_t)t * nblk + b];
    }
    __syncthreads();
    int beg = b * EPB, end = min(ne, beg + EPB), cnt = end - beg;
    int cnt4 = cnt >> 2;
    const int4* keys4 = (const int4*)(keys + beg);
    for (int i = tid; i < cnt4; i += 256) {
        int4 k = keys4[i];
        atomicAdd(&h[k.x >> shift], 1u);
        atomicAdd(&h[k.y >> shift], 1u);
        atomicAdd(&h[k.z >> shift], 1u);
        atomicAdd(&h[k.w >> shift], 1u);
    }
    for (int i = cnt4 * 4 + tid; i < cnt; i += 256) atomicAdd(&h[keys[beg + i] >> shift], 1u);
    __syncthreads();
    unsigned v0, v1, v2, v3;
    int q = tid * 4;
    v0 = h[q]; v1 = h[q + 1]; v2 = h[q + 2]; v3 = h[q + 3];
    sc[tid] = v0 + v1 + v2 + v3;
    __syncthreads();
    for (int dd = 1; dd < 256; dd <<= 1) {
        unsigned add = (tid >= dd) ? sc[tid - dd] : 0u;
        __syncthreads();
        sc[tid] += add;
        __syncthreads();
    }
    unsigned ex = (tid == 0) ? 0u : sc[tid - 1];
    lb[q]     = ex;
    lb[q + 1] = ex + v0;
    lb[q + 2] = ex + v0 + v1;
    lb[q + 3] = ex + v0 + v1 + v2;
    __syncthreads();
    for (int t = tid; t < 1024; t += 256) h[t] = 0;
    __syncthreads();
    unsigned mask = (1u << shift) - 1u;
    const int4* vals4 = (const int4*)(vals + beg);
    const float4* w4 = (const float4*)(w + beg);
    for (int i = tid; i < cnt4; i += 256) {
        int4 k = keys4[i];
        int4 v = vals4[i];
        float4 ww = w4[i];
        {
            unsigned bkt = (unsigned)k.x >> shift;
            unsigned r = atomicAdd(&h[bkt], 1u);
            unsigned slot = lb[bkt] + r;
            stage[slot] = make_int2(__float_as_int(ww.x),
                                    (v.x << shift) | (unsigned)(k.x & (int)mask));
            sbkt[slot] = (unsigned short)bkt;
        }
        {
            unsigned bkt = (unsigned)k.y >> shift;
            unsigned r = atomicAdd(&h[bkt], 1u);
            unsigned slot = lb[bkt] + r;
            stage[slot] = make_int2(__float_as_int(ww.y),
                                    (v.y << shift) | (unsigned)(k.y & (int)mask));
            sbkt[slot] = (unsigned short)bkt;
        }
        {
            unsigned bkt = (unsigned)k.z >> shift;
            unsigned r = atomicAdd(&h[bkt], 1u);
            unsigned slot = lb[bkt] + r;
            stage[slot] = make_int2(__float_as_int(ww.z),
                                    (v.z << shift) | (unsigned)(k.z & (int)mask));
            sbkt[slot] = (unsigned short)bkt;
        }
        {
            unsigned bkt = (unsigned)k.w >> shift;
            unsigned r = atomicAdd(&h[bkt], 1u);
            unsigned slot = lb[bkt] + r;
            stage[slot] = make_int2(__float_as_int(ww.w),
                                    (v.w << shift) | (unsigned)(k.w & (int)mask));
            sbkt[slot] = (unsigned short)bkt;
        }
    }
    for (int i = cnt4 * 4 + tid; i < cnt; i += 256) {
        int k = keys[beg + i];
        unsigned bkt = (unsigned)k >> shift;
        unsigned r = atomicAdd(&h[bkt], 1u);
        unsigned slot = lb[bkt] + r;
        stage[slot] = make_int2(__float_as_int(w[beg + i]),
                                (vals[beg + i] << shift) | (unsigned)(k & (int)mask));
        sbkt[slot] = (unsigned short)bkt;
    }
    __syncthreads();
    for (int i = tid; i < cnt; i += 256) {
        unsigned bb = sbkt[i];
        bucketed[gb[bb] + ((unsigned)i - lb[bb])] = stage[i];
    }
}

// per-bucket low-bit histogram -> per-node degree (generic, for C direction)
__global__ __launch_bounds__(256) void kDeg(const int2* __restrict__ bucketed,
                                            const unsigned* __restrict__ scanned,
                                            unsigned* __restrict__ deg,
                                            int nnodes, int nblk, int lowbits) {
    __shared__ unsigned h[1024];
    int d = blockIdx.x, tid = threadIdx.x;
    int W = 1 << lowbits;
    unsigned mask = (unsigned)(W - 1);
    unsigned base = scanned[(size_t)d * nblk], next = scanned[(size_t)(d + 1) * nblk];
    for (int t = tid; t < W; t += 256) h[t] = 0;
    __syncthreads();
    for (unsigned i = base + tid; i < next; i += 256)
        atomicAdd(&h[(unsigned)bucketed[i].y & mask], 1u);
    __syncthreads();
    int lo = d << lowbits;
    for (int t = tid; t < W; t += 256) {
        int node = lo + t;
        if (node < nnodes) deg[node] = h[t];
    }
}

// V direction: degree + fused pack of (c, x, rsqrt(deg)) in one pass
__global__ __launch_bounds__(256) void kDegPackV(const int2* __restrict__ bucketed,
                                                 const unsigned* __restrict__ scanned,
                                                 const float* __restrict__ var_c,
                                                 const float* __restrict__ var_x,
                                                 unsigned* __restrict__ deg,
                                                 float4* __restrict__ vcr,
                                                 int nnodes, int nblk) {
    __shared__ unsigned h[1024];
    int d = blockIdx.x, tid = threadIdx.x;
    unsigned base = scanned[(size_t)d * nblk], next = scanned[(size_t)(d + 1) * nblk];
    for (int t = tid; t < 1024; t += 256) h[t] = 0;
    __syncthreads();
    for (unsigned i = base + tid; i < next; i += 256)
        atomicAdd(&h[(unsigned)bucketed[i].y & 1023u], 1u);
    __syncthreads();
    int lo = d << 10;
    for (int t = tid; t < 1024; t += 256) {
        int node = lo + t;
        if (node < nnodes) {
            unsigned dg = h[t];
            deg[node] = dg;
            float rs = rsqrtf(fmaxf((float)dg, 1.0f));
            vcr[node] = make_float4(var_c[node], var_x[node], rs, 0.0f);
        }
    }
}

// NOTE: no __restrict__ -- used in-place (in == out) for the deg->start scans
__global__ __launch_bounds__(256) void k_scan_blocks(const unsigned int* in,
                                                     unsigned int* out,
                                                     unsigned int* bsum,
                                                     int n) {
    __shared__ unsigned int sT[256];
    int base = blockIdx.x * 1024 + threadIdx.x * 4;
    unsigned int v0 = 0, v1 = 0, v2 = 0, v3 = 0;
    if (base + 3 < n) {
        uint4 u = *(const uint4*)(in + base);
        v0 = u.x; v1 = u.y; v2 = u.z; v3 = u.w;
    } else {
        if (base     < n) v0 = in[base];
        if (base + 1 < n) v1 = in[base + 1];
        if (base + 2 < n) v2 = in[base + 2];
        if (base + 3 < n) v3 = in[base + 3];
    }
    sT[threadIdx.x] = v0 + v1 + v2 + v3;
    __syncthreads();
    for (int d = 1; d < 256; d <<= 1) {
        unsigned int add = (threadIdx.x >= (unsigned)d) ? sT[threadIdx.x - d] : 0u;
        __syncthreads();
        sT[threadIdx.x] += add;
        __syncthreads();
    }
    unsigned int excl = (threadIdx.x == 0) ? 0u : sT[threadIdx.x - 1];
    if (base     < n) out[base]     = excl;
    if (base + 1 < n) out[base + 1] = excl + v0;
    if (base + 2 < n) out[base + 2] = excl + v0 + v1;
    if (base + 3 < n) out[base + 3] = excl + v0 + v1 + v2;
    if (threadIdx.x == 255 && bsum) bsum[blockIdx.x] = sT[255];
}

// single-block looped exclusive scan (any n)
__global__ __launch_bounds__(256) void k_scan_mid(const unsigned* __restrict__ in,
                                                  unsigned* __restrict__ out, int n) {
    __shared__ unsigned sT[256];
    __shared__ unsigned carry;
    if (threadIdx.x == 0) carry = 0;
    __syncthreads();
    for (int base = 0; base < n; base += 256) {
        int i = base + threadIdx.x;
        unsigned v = (i < n) ? in[i] : 0u;
        sT[threadIdx.x] = v;
        __syncthreads();
        for (int d = 1; d < 256; d <<= 1) {
            unsigned add = (threadIdx.x >= (unsigned)d) ? sT[threadIdx.x - d] : 0u;
            __syncthreads();
            sT[threadIdx.x] += add;
            __syncthreads();
        }
        unsigned excl = carry + ((threadIdx.x == 0) ? 0u : sT[threadIdx.x - 1]);
        if (i < n) out[i] = excl;
        __syncthreads();
        if (threadIdx.x == 255) carry += sT[255];
        __syncthreads();
    }
}

__global__ __launch_bounds__(256) void k_scan_add(unsigned int* __restrict__ data,
                                                  const unsigned int* __restrict__ bscan,
                                                  int n) {
    int base = blockIdx.x * 1024 + threadIdx.x * 4;
    unsigned int add = bscan[blockIdx.x];
    if (base + 3 < n) {
        uint4 u = *(const uint4*)(data + base);
        u.x += add; u.y += add; u.z += add; u.w += add;
        *(uint4*)(data + base) = u;
    } else {
        if (base     < n) data[base]     += add;
        if (base + 1 < n) data[base + 1] += add;
        if (base + 2 < n) data[base + 2] += add;
        if (base + 3 < n) data[base + 3] += add;
    }
}

// ============================================================================
// Node pipeline
// ============================================================================

// embed+accumulate one staged edge: identical op order to the Xs-table path
#define EMBADD(e)                                                             \
    {                                                                         \
        float4 vv = vcr[(size_t)(e).y];                                       \
        float we = __int_as_float((e).x);                                     \
        float t0 = fmaf(vv.x, wv0[0], fmaf(vv.y, wv1[0], bvr[0]));            \
        float t1 = fmaf(vv.x, wv0[1], fmaf(vv.y, wv1[1], bvr[1]));            \
        float t2 = fmaf(vv.x, wv0[2], fmaf(vv.y, wv1[2], bvr[2]));            \
        float t3 = fmaf(vv.x, wv0[3], fmaf(vv.y, wv1[3], bvr[3]));            \
        acc.x = fmaf(we, fmaxf(t0, 0.f) * vv.z, acc.x);                       \
        acc.y = fmaf(we, fmaxf(t1, 0.f) * vv.z, acc.y);                       \
        acc.z = fmaf(we, fmaxf(t2, 0.f) * vv.z, acc.z);                       \
        acc.w = fmaf(we, fmaxf(t3, 0.f) * vv.z, acc.w);                       \
    }

#define EMB4(eA, eB, eC, eD)                                                  \
    {                                                                         \
        float4 vA = vcr[(size_t)(eA).y];                                      \
        float4 vB = vcr[(size_t)(eB).y];                                      \
        float4 vC = vcr[(size_t)(eC).y];                                      \
        float4 vD = vcr[(size_t)(eD).y];                                      \
        float wA = __int_as_float((eA).x), wB = __int_as_float((eB).x);       \
        float wC = __int_as_float((eC).x), wD = __int_as_float((eD).x);       \
        float t0, t1, t2, t3;                                                 \
        t0 = fmaf(vA.x, wv0[0], fmaf(vA.y, wv1[0], bvr[0]));                  \
        t1 = fmaf(vA.x, wv0[1], fmaf(vA.y, wv1[1], bvr[1]));                  \
        t2 = fmaf(vA.x, wv0[2], fmaf(vA.y, wv1[2], bvr[2]));                  \
        t3 = fmaf(vA.x, wv0[3], fmaf(vA.y, wv1[3], bvr[3]));                  \
        acc.x = fmaf(wA, fmaxf(t0, 0.f) * vA.z, acc.x);                       \
        acc.y = fmaf(wA, fmaxf(t1, 0.f) * vA.z, acc.y);                       \
        acc.z = fmaf(wA, fmaxf(t2, 0.f) * vA.z, acc.z);                       \
        acc.w = fmaf(wA, fmaxf(t3, 0.f) * vA.z, acc.w);                       \
        t0 = fmaf(vB.x, wv0[0], fmaf(vB.y, wv1[0], bvr[0]));                  \
        t1 = fmaf(vB.x, wv0[1], fmaf(vB.y, wv1[1], bvr[1]));                  \
        t2 = fmaf(vB.x, wv0[2], fmaf(vB.y, wv1[2], bvr[2]));                  \
        t3 = fmaf(vB.x, wv0[3], fmaf(vB.y, wv1[3], bvr[3]));                  \
        acc.x = fmaf(wB, fmaxf(t0, 0.f) * vB.z, acc.x);                       \
        acc.y = fmaf(wB, fmaxf(t1, 0.f) * vB.z, acc.y);                       \
        acc.z = fmaf(wB, fmaxf(t2, 0.f) * vB.z, acc.z);                       \
        acc.w = fmaf(wB, fmaxf(t3, 0.f) * vB.z, acc.w);                       \
        t0 = fmaf(vC.x, wv0[0], fmaf(vC.y, wv1[0], bvr[0]));                  \
        t1 = fmaf(vC.x, wv0[1], fmaf(vC.y, wv1[1], bvr[1]));                  \
        t2 = fmaf(vC.x, wv0[2], fmaf(vC.y, wv1[2], bvr[2]));                  \
        t3 = fmaf(vC.x, wv0[3], fmaf(vC.y, wv1[3], bvr[3]));                  \
        acc.x = fmaf(wC, fmaxf(t0, 0.f) * vC.z, acc.x);                       \
        acc.y = fmaf(wC, fmaxf(t1, 0.f) * vC.z, acc.y);                       \
        acc.z = fmaf(wC, fmaxf(t2, 0.f) * vC.z, acc.z);                       \
        acc.w = fmaf(wC, fmaxf(t3, 0.f) * vC.z, acc.w);                       \
        t0 = fmaf(vD.x, wv0[0], fmaf(vD.y, wv1[0], bvr[0]));                  \
        t1 = fmaf(vD.x, wv0[1], fmaf(vD.y, wv1[1], bvr[1]));                  \
        t2 = fmaf(vD.x, wv0[2], fmaf(vD.y, wv1[2], bvr[2]));                  \
        t3 = fmaf(vD.x, wv0[3], fmaf(vD.y, wv1[3], bvr[3]));                  \
        acc.x = fmaf(wD, fmaxf(t0, 0.f) * vD.z, acc.x);                       \
        acc.y = fmaf(wD, fmaxf(t1, 0.f) * vD.z, acc.y);                       \
        acc.z = fmaf(wD, fmaxf(t2, 0.f) * vD.z, acc.z);                       \
        acc.w = fmaf(wD, fmaxf(t3, 0.f) * vD.z, acc.w);                       \
    }

// conv1 fused, half-bucket of 256 con nodes; on-the-fly var embedding from vcr
__global__ __launch_bounds__(512) void kF_con(const int2* __restrict__ bucketed,
                                              const unsigned* __restrict__ scanned,
                                              const unsigned* __restrict__ startC,
                                              const float4* __restrict__ vcr,
                                              const float* __restrict__ Wv,
                                              const float* __restrict__ bv,
                                              const float* __restrict__ W2,
                                              const float* __restrict__ b2,
                                              float* __restrict__ hs, int nblk, int netot) {
    __shared__ unsigned sraw[257], cr[256];
    __shared__ float sWv[20], sbv[10], sW[100], sb[10];
    __shared__ int2 stage[FCAP];
    int tid = threadIdx.x;
    int d = blockIdx.x >> 1, half = blockIdx.x & 1;
    int gbase = (d << 9) + half * 256;
    for (int t = tid; t < 100; t += 512) sW[t] = W2[t];
    if (tid < 10) sb[tid] = b2[tid];
    if (tid < 20) sWv[tid] = Wv[tid];
    if (tid >= 20 && tid < 30) sbv[tid - 20] = bv[tid - 20];
    for (int t = tid; t < 257; t += 512) {
        int g = gbase + t;
        sraw[t] = (g < NCON) ? startC[g] : (unsigned)netot;
    }
    if (tid < 256) cr[tid] = 0;
    __syncthreads();
    unsigned own_beg = sraw[0], own_end = sraw[256];
    bool fit = (int)(own_end - own_beg) <= FCAP;
    unsigned bbase = scanned[(size_t)d * nblk];
    unsigned bnext = scanned[(size_t)(d + 1) * nblk];
    int bsz = (int)(bnext - bbase);
    if (fit) {
        for (int i = tid; i < bsz; i += 512) {
            int2 p = bucketed[bbase + i];
            unsigned low = (unsigned)p.y & 511u;
            if ((int)(low >> 8) == half) {
                unsigned nl = low & 255u;
                unsigned r = atomicAdd(&cr[nl], 1u);
                stage[sraw[nl] - own_beg + r] = make_int2(p.x, p.y >> 9);
            }
        }
    }
    __syncthreads();
    int quad = tid >> 2, lane = tid & 3, c0 = lane * 4;
    float wv0[4], wv1[4], bvr[4];
#pragma unroll
    for (int k = 0; k < 4; k++) {
        int j = c0 + k;
        wv0[k] = (j < 10) ? sWv[j] : 0.f;
        wv1[k] = (j < 10) ? sWv[10 + j] : 0.f;
        bvr[k] = (j < 10) ? sbv[j] : 0.f;
    }
#pragma unroll
    for (int rr = 0; rr < 2; rr++) {
        int nl = rr * 128 + quad;
        int g = gbase + nl;
        if (g >= NCON) continue;
        float4 acc = make_float4(0.f, 0.f, 0.f, 0.f);
        unsigned cnt;
        if (fit) {
            unsigned beg = sraw[nl] - own_beg;
            cnt = cr[nl];
            unsigned end = beg + cnt, p = beg;
            for (; p + 4 <= end; p += 4) {
                int2 e0 = stage[p], e1 = stage[p + 1], e2 = stage[p + 2], e3 = stage[p + 3];
                EMB4(e0, e1, e2, e3);
            }
            for (; p < end; ++p) {
                int2 e = stage[p];
                EMBADD(e);
            }
        } else {   // statistically unreachable safety path
            cnt = 0;
            unsigned target = (unsigned)(half * 256 + nl);
            for (int i = 0; i < bsz; ++i) {
                int2 p = bucketed[bbase + i];
                if (((unsigned)p.y & 511u) == target) {
                    ++cnt;
                    int2 e = make_int2(p.x, p.y >> 9);
                    EMBADD(e);
                }
            }
        }
        float rs = rsqrtf(fmaxf((float)cnt, 1.0f));
        float a[10];
        a[0] = __shfl(acc.x, 0, 4); a[1] = __shfl(acc.y, 0, 4);
        a[2] = __shfl(acc.z, 0, 4); a[3] = __shfl(acc.w, 0, 4);
        a[4] = __shfl(acc.x, 1, 4); a[5] = __shfl(acc.y, 1, 4);
        a[6] = __shfl(acc.z, 1, 4); a[7] = __shfl(acc.w, 1, 4);
        a[8] = __shfl(acc.x, 2, 4); a[9] = __shfl(acc.y, 2, 4);
#pragma unroll
        for (int j = 0; j < 10; j++) a[j] *= rs;
        float o[12];
#pragma unroll
        for (int k = 0; k < 10; k++) {
            float t = sb[k];
#pragma unroll
            for (int j = 0; j < 10; j++) t = fmaf(a[j], sW[j * 10 + k], t);
            o[k] = fmaxf(t, 0.0f) * rs;   // relu + prescale for conv2
        }
        o[10] = 0.0f; o[11] = 0.0f;
        float4 wv = (lane < 3) ? make_float4(o[c0], o[c0 + 1], o[c0 + 2], o[c0 + 3])
                               : make_float4(0.f, 0.f, 0.f, 0.f);
        *(float4*)(hs + (size_t)g * 16 + c0) = wv;
    }
}

#define GATHER4(eA, eB, eC, eD, TAB)                                          \
    {                                                                         \
        float4 v0 = *(const float4*)(TAB + (size_t)(eA).y * 16 + c0);         \
        float4 v1 = *(const float4*)(TAB + (size_t)(eB).y * 16 + c0);         \
        float4 v2 = *(const float4*)(TAB + (size_t)(eC).y * 16 + c0);         \
        float4 v3 = *(const float4*)(TAB + (size_t)(eD).y * 16 + c0);         \
        float w0 = __int_as_float((eA).x), w1 = __int_as_float((eB).x);       \
        float w2 = __int_as_float((eC).x), w3 = __int_as_float((eD).x);       \
        acc.x = fmaf(w0, v0.x, acc.x); acc.y = fmaf(w0, v0.y, acc.y);         \
        acc.z = fmaf(w0, v0.z, acc.z); acc.w = fmaf(w0, v0.w, acc.w);         \
        acc.x = fmaf(w1, v1.x, acc.x); acc.y = fmaf(w1, v1.y, acc.y);         \
        acc.z = fmaf(w1, v1.z, acc.z); acc.w = fmaf(w1, v1.w, acc.w);         \
        acc.x = fmaf(w2, v2.x, acc.x); acc.y = fmaf(w2, v2.y, acc.y);         \
        acc.z = fmaf(w2, v2.z, acc.z); acc.w = fmaf(w2, v2.w, acc.w);         \
        acc.x = fmaf(w3, v3.x, acc.x); acc.y = fmaf(w3, v3.y, acc.y);         \
        acc.z = fmaf(w3, v3.z, acc.z); acc.w = fmaf(w3, v3.w, acc.w);         \
    }

// conv2 fused, half-bucket of 512 var nodes: rank-stage, gather hs, dense + MLP,
// per-block partial mean.
__global__ __launch_bounds__(512) void kF_fin(const int2* __restrict__ bucketed,
                                              const unsigned* __restrict__ scanned,
                                              const unsigned* __restrict__ startV,
                                              const float* __restrict__ feat,
                                              const float* __restrict__ W2,
                                              const float* __restrict__ b2,
                                              const float* __restrict__ Wo1,
                                              const float* __restrict__ bo1,
                                              const float* __restrict__ Wo2,
                                              const float* __restrict__ bo2,
                                              const float* __restrict__ Wo3,
                                              const float* __restrict__ bo3,
                                              double* __restrict__ partials, int nblk, int netot) {
    __shared__ unsigned sraw[513], cr[512];
    __shared__ float sW2[100], sb2[10], sWo1[100], sbo1[10], sWo2[100], sbo2[10], sWo3[10], sbo3v;
    __shared__ int2 stage[FCAP];
    __shared__ double red[512];
    int tid = threadIdx.x;
    int d = blockIdx.x >> 1, half = blockIdx.x & 1;
    int gbase = (d << 10) + half * 512;
    for (int t = tid; t < 100; t += 512) { sW2[t] = W2[t]; sWo1[t] = Wo1[t]; sWo2[t] = Wo2[t]; }
    if (tid < 10) {
        sb2[tid] = b2[tid]; sbo1[tid] = bo1[tid]; sbo2[tid] = bo2[tid]; sWo3[tid] = Wo3[tid];
    }
    if (tid == 0) sbo3v = bo3[0];
    for (int t = tid; t < 513; t += 512) {
        int g = gbase + t;
        sraw[t] = (g < NVAR) ? startV[g] : (unsigned)netot;
    }
    cr[tid] = 0;
    __syncthreads();
    unsigned own_beg = sraw[0], own_end = sraw[512];
    bool fit = (int)(own_end - own_beg) <= FCAP;
    unsigned bbase = scanned[(size_t)d * nblk];
    unsigned bnext = scanned[(size_t)(d + 1) * nblk];
    int bsz = (int)(bnext - bbase);
    if (fit) {
        for (int i = tid; i < bsz; i += 512) {
            int2 p = bucketed[bbase + i];
            unsigned low = (unsigned)p.y & 1023u;
            if ((int)(low >> 9) == half) {
                unsigned nl = low & 511u;
                unsigned r = atomicAdd(&cr[nl], 1u);
                stage[sraw[nl] - own_beg + r] = make_int2(p.x, p.y >> 10);
            }
        }
    }
    __syncthreads();
    int quad = tid >> 2, lane = tid & 3, c0 = lane * 4;
    double accd = 0.0;
#pragma unroll
    for (int rr = 0; rr < 4; rr++) {
        int nl = rr * 128 + quad;
        int g = gbase + nl;
        if (g >= NVAR) continue;
        float4 acc = make_float4(0.f, 0.f, 0.f, 0.f);
        unsigned cnt;
        if (fit) {
            unsigned beg = sraw[nl] - own_beg;
            cnt = cr[nl];
            unsigned end = beg + cnt, p = beg;
            for (; p + 4 <= end; p += 4) {
                int2 e0 = stage[p], e1 = stage[p + 1], e2 = stage[p + 2], e3 = stage[p + 3];
                GATHER4(e0, e1, e2, e3, feat);
            }
            for (; p < end; ++p) {
                int2 e = stage[p];
                float4 v = *(const float4*)(feat + (size_t)e.y * 16 + c0);
                float we = __int_as_float(e.x);
                acc.x = fmaf(we, v.x, acc.x); acc.y = fmaf(we, v.y, acc.y);
                acc.z = fmaf(we, v.z, acc.z); acc.w = fmaf(we, v.w, acc.w);
            }
        } else {   // statistically unreachable safety path
            cnt = 0;
            unsigned target = (unsigned)(half * 512 + nl);
            for (int i = 0; i < bsz; ++i) {
                int2 p = bucketed[bbase + i];
                if (((unsigned)p.y & 1023u) == target) {
                    ++cnt;
                    float4 v = *(const float4*)(feat + (size_t)((unsigned)p.y >> 10) * 16 + c0);
                    float we = __int_as_float(p.x);
                    acc.x = fmaf(we, v.x, acc.x); acc.y = fmaf(we, v.y, acc.y);
                    acc.z = fmaf(we, v.z, acc.z); acc.w = fmaf(we, v.w, acc.w);
                }
            }
        }
        float rs = rsqrtf(fmaxf((float)cnt, 1.0f));
        float a[10];
        a[0] = __shfl(acc.x, 0, 4); a[1] = __shfl(acc.y, 0, 4);
        a[2] = __shfl(acc.z, 0, 4); a[3] = __shfl(acc.w, 0, 4);
        a[4] = __shfl(acc.x, 1, 4); a[5] = __shfl(acc.y, 1, 4);
        a[6] = __shfl(acc.z, 1, 4); a[7] = __shfl(acc.w, 1, 4);
        a[8] = __shfl(acc.x, 2, 4); a[9] = __shfl(acc.y, 2, 4);
#pragma unroll
        for (int j = 0; j < 10; j++) a[j] *= rs;
        float hh[10], z[10];
#pragma unroll
        for (int k = 0; k < 10; k++) {
            float t = sb2[k];
#pragma unroll
            for (int j = 0; j < 10; j++) t = fmaf(a[j], sW2[j * 10 + k], t);
            hh[k] = fmaxf(t, 0.0f);
        }
#pragma unroll
        for (int k = 0; k < 10; k++) {
            float t = sbo1[k];
#pragma unroll
            for (int j = 0; j < 10; j++) t = fmaf(hh[j], sWo1[j * 10 + k], t);
            z[k] = fmaxf(t, 0.0f);
        }
        float t3 = sbo3v;
#pragma unroll
        for (int k = 0; k < 10; k++) {
            float t = sbo2[k];
#pragma unroll
            for (int j = 0; j < 10; j++) t = fmaf(z[j], sWo2[j * 10 + k], t);
            t = fmaxf(t, 0.0f);
            t3 = fmaf(t, sWo3[k], t3);
        }
        if (lane == 0) accd += (double)t3;
    }
    red[tid] = accd;
    __syncthreads();
    for (int off = 256; off > 0; off >>= 1) {
        if (tid < off) red[tid] += red[tid + off];
        __syncthreads();
    }
    if (tid == 0) partials[blockIdx.x] = red[0];
}

__global__ __launch_bounds__(256) void k_out(const double* __restrict__ partials, int np,
                                             float* __restrict__ out) {
    __shared__ double red[256];
    double a = 0.0;
    for (int i = threadIdx.x; i < np; i += blockDim.x) a += partials[i];
    red[threadIdx.x] = a;
    __syncthreads();
    for (int off = 128; off > 0; off >>= 1) {
        if (threadIdx.x < off) red[threadIdx.x] += red[threadIdx.x + off];
        __syncthreads();
    }
    if (threadIdx.x == 0) out[0] = (float)(red[0] / (double)NVAR);
}

// ============================================================================
// Launch
// ============================================================================

extern "C" void kernel_launch(void* const* d_in, const int* in_sizes, int n_in,
                              void* d_out, int out_size, void* d_ws, size_t ws_size,
                              hipStream_t stream) {
    const float* var_c  = (const float*)d_in[0];
    const float* var_x  = (const float*)d_in[1];
    const int*   e_src  = (const int*)d_in[3];
    const int*   e_dst  = (const int*)d_in[4];
    const float* e_w    = (const float*)d_in[5];
    const float* Wv     = (const float*)d_in[6];
    const float* bv     = (const float*)d_in[7];
    const float* W2     = (const float*)d_in[12];
    const float* b2     = (const float*)d_in[13];
    const float* Wo1    = (const float*)d_in[14];
    const float* bo1    = (const float*)d_in[15];
    const float* Wo2    = (const float*)d_in[16];
    const float* bo2    = (const float*)d_in[17];
    const float* Wo3    = (const float*)d_in[18];
    const float* bo3    = (const float*)d_in[19];
    float* out = (float*)d_out;
    const int ne = in_sizes[3];
    (void)n_in; (void)out_size; (void)ws_size;

    const int B = 256;
    const int nblkA = (ne + EPB - 1) / EPB;       // 977
    const int scanN = 1024 * nblkA;               // ~1.0M
    const int NBs   = (scanN + 1023) / 1024;      // 977
    const int BKV   = (NVAR + 1023) >> 10;        // 977 (shift 10)
    const int BKC   = (NCON + 511) >> 9;          // 977 (shift 9)
    const int NBV   = (NVAR + 1023) / 1024;       // 977
    const int NBC   = (NCON + 1023) / 1024;       // 489
    const int ne4   = ne / 4;

    char* ws = (char*)d_ws;
    size_t off = 0;
    auto walloc = [&](size_t bytes) {
        void* p = ws + off;
        off = (off + bytes + 255) & ~(size_t)255;
        return p;
    };

    int2*     bucketedV = (int2*)walloc((size_t)ne * 8);           // 64 MB
    int2*     bucketedC = (int2*)walloc((size_t)ne * 8);           // 64 MB
    float4*   vcr       = (float4*)walloc((size_t)NVAR * 16);      // 16 MB
    float*    hs64      = (float*)walloc((size_t)NCON * 16 * 4);   // 32 MB
    unsigned* scannedV  = (unsigned*)walloc((size_t)scanN * 4);    //  4 MB
    unsigned* scannedC  = (unsigned*)walloc((size_t)scanN * 4);    //  4 MB
    unsigned* bhV       = (unsigned*)walloc((size_t)scanN * 4);    //  4 MB
    unsigned* bhC       = (unsigned*)walloc((size_t)scanN * 4);    //  4 MB
    unsigned* bsumA     = (unsigned*)walloc(8192);
    unsigned* bscanA    = (unsigned*)walloc(8192);
    double*   partials  = (double*)walloc((size_t)(BKV * 2) * 8 + 64);
    // overlays: bhV dead after its bucket scan -> deg_var (in-place scan -> startV)
    //           bhC dead after its bucket scan -> deg_con (in-place scan -> startC)
    unsigned* deg_var   = bhV;
    unsigned* deg_con   = bhC;

    // 1. fused dual histogram
    kA_hist2<<<nblkA, B, 0, stream>>>((const int4*)e_src, (const int4*)e_dst,
                                      bhV, bhC, ne4, nblkA);

    // 2. bucket-level scans -> global segment bases
    k_scan_blocks<<<NBs, B, 0, stream>>>(bhV, scannedV, bsumA, scanN);
    k_scan_mid   <<<1,   B, 0, stream>>>(bsumA, bscanA, NBs);
    k_scan_add   <<<NBs, B, 0, stream>>>(scannedV, bscanA, scanN);
    k_scan_blocks<<<NBs, B, 0, stream>>>(bhC, scannedC, bsumA, scanN);
    k_scan_mid   <<<1,   B, 0, stream>>>(bsumA, bscanA, NBs);
    k_scan_add   <<<NBs, B, 0, stream>>>(scannedC, bscanA, scanN);

    // 3. V-direction bucketing (key=src var, val=dst con); bhV now dead
    kA_scat<<<nblkA, B, 0, stream>>>(e_src, e_dst, e_w, scannedV, bucketedV, ne, 10, nblkA);

    // 4. per-node var degrees + fused (c,x,rsqrt) pack
    kDegPackV<<<BKV, B, 0, stream>>>(bucketedV, scannedV, var_c, var_x,
                                     deg_var, vcr, NVAR, nblkA);

    // 5. in-place exclusive scan deg_var -> startV
    k_scan_blocks<<<NBV, B, 0, stream>>>(deg_var, deg_var, bsumA, NVAR);
    k_scan_mid   <<<1,   B, 0, stream>>>(bsumA, bscanA, NBV);
    k_scan_add   <<<NBV, B, 0, stream>>>(deg_var, bscanA, NVAR);

    // 6. C-direction bucketing (key=dst con, val=src var); bhC now dead
    kA_scat<<<nblkA, B, 0, stream>>>(e_dst, e_src, e_w, scannedC, bucketedC, ne, 9, nblkA);

    // 7. per-node con degrees (overlay on bhC), in-place scan -> startC
    kDeg<<<BKC, B, 0, stream>>>(bucketedC, scannedC, deg_con, NCON, nblkA, 9);
    k_scan_blocks<<<NBC, B, 0, stream>>>(deg_con, deg_con, bsumA, NCON);
    k_scan_mid   <<<1,   B, 0, stream>>>(bsumA, bscanA, NBC);
    k_scan_add   <<<NBC, B, 0, stream>>>(deg_con, bscanA, NCON);

    // 8. conv1 fused (half-buckets, on-the-fly embedding from vcr)
    kF_con<<<BKC * 2, 512, 0, stream>>>(bucketedC, scannedC, deg_con, vcr, Wv, bv,
                                        W2, b2, hs64, nblkA, ne);

    // 9. conv2 fused (half-buckets) + MLP + partials
    kF_fin<<<BKV * 2, 512, 0, stream>>>(bucketedV, scannedV, deg_var, hs64, W2, b2,
                                        Wo1, bo1, Wo2, bo2, Wo3, bo3, partials, nblkA, ne);

    // 10. final mean
    k_out<<<1, B, 0, stream>>>(partials, BKV * 2, out);
}

// Round 15
// 526.143 us; speedup vs baseline: 1.1671x; 1.0725x over previous
//
#include <hip/hip_runtime.h>

#define NVAR 1000000
#define NCON 500000
#define EPB 8192     // edges per pass-A block
#define FCAP 4480    // per-half-bucket LDS stage capacity (mean 4096, sd 64 -> +6 sigma)

// ============================================================================
// Sort front-end
// ============================================================================

// fused dual histogram; writes BLOCK-MAJOR bhT[b][t] (coalesced)
__global__ __launch_bounds__(256) void kA_hist2(const int4* __restrict__ src4,
                                                const int4* __restrict__ dst4,
                                                unsigned* __restrict__ bhTV,
                                                unsigned* __restrict__ bhTC,
                                                int ne4) {
    __shared__ unsigned hv[1024], hc[1024];
    int tid = threadIdx.x, b = blockIdx.x;
    for (int t = tid; t < 1024; t += 256) { hv[t] = 0; hc[t] = 0; }
    __syncthreads();
    int beg = b * (EPB / 4), end = min(ne4, beg + (EPB / 4));
    for (int i = beg + tid; i < end; i += 256) {
        int4 s = src4[i];
        int4 d = dst4[i];
        atomicAdd(&hv[s.x >> 10], 1u); atomicAdd(&hv[s.y >> 10], 1u);
        atomicAdd(&hv[s.z >> 10], 1u); atomicAdd(&hv[s.w >> 10], 1u);
        atomicAdd(&hc[d.x >> 9], 1u);  atomicAdd(&hc[d.y >> 9], 1u);
        atomicAdd(&hc[d.z >> 9], 1u);  atomicAdd(&hc[d.w >> 9], 1u);
    }
    __syncthreads();
    for (int t = tid; t < 1024; t += 256) {
        bhTV[(size_t)b * 1024 + t] = hv[t];
        bhTC[(size_t)b * 1024 + t] = hc[t];
    }
}

// tiled transpose: in[R][1024] (block-major) -> out[1024][R] (bucket-major)
__global__ __launch_bounds__(256) void k_transpose(const unsigned* __restrict__ in,
                                                   unsigned* __restrict__ out, int R) {
    __shared__ unsigned tile[32][33];
    int ct = blockIdx.x, rt = blockIdx.y;
    int tx = threadIdx.x & 31, ty = threadIdx.x >> 5;   // 32 x 8
#pragma unroll
    for (int k = 0; k < 4; k++) {
        int r = rt * 32 + ty + k * 8, c = ct * 32 + tx;
        tile[ty + k * 8][tx] = (r < R) ? in[(size_t)r * 1024 + c] : 0u;
    }
    __syncthreads();
#pragma unroll
    for (int k = 0; k < 4; k++) {
        int r2 = rt * 32 + tx, c2 = ct * 32 + ty + k * 8;
        if (r2 < R) out[(size_t)c2 * R + r2] = tile[tx][ty + k * 8];
    }
}

// rank-stage payload in LDS, emit slots in order (binary search over lb).
// Histogram LOADED from bhT (computed in kA_hist2) -> no phase-0 key re-read.
__global__ __launch_bounds__(256) void kA_scat(const int* __restrict__ keys,
                                               const int* __restrict__ vals,
                                               const float* __restrict__ w,
                                               const unsigned* __restrict__ bhT,
                                               const unsigned int* __restrict__ scanned,
                                               int2* __restrict__ bucketed,
                                               int ne, int shift, int nblk) {
    __shared__ unsigned int h[1024];
    __shared__ unsigned int lb[1024];
    __shared__ unsigned int gb[1024];
    __shared__ unsigned int sc[256];
    __shared__ int2 stage[EPB];
    int tid = threadIdx.x, b = blockIdx.x;
    for (int t = tid; t < 1024; t += 256) {
        h[t] = bhT[(size_t)b * 1024 + t];               // coalesced histogram load
        gb[t] = scanned[(size_t)t * nblk + b];
    }
    __syncthreads();
    int beg = b * EPB, end = min(ne, beg + EPB), cnt = end - beg;
    // exclusive scan h -> lb
    unsigned v0, v1, v2, v3;
    int q = tid * 4;
    v0 = h[q]; v1 = h[q + 1]; v2 = h[q + 2]; v3 = h[q + 3];
    sc[tid] = v0 + v1 + v2 + v3;
    __syncthreads();
    for (int dd = 1; dd < 256; dd <<= 1) {
        unsigned add = (tid >= dd) ? sc[tid - dd] : 0u;
        __syncthreads();
        sc[tid] += add;
        __syncthreads();
    }
    unsigned ex = (tid == 0) ? 0u : sc[tid - 1];
    lb[q]     = ex;
    lb[q + 1] = ex + v0;
    lb[q + 2] = ex + v0 + v1;
    lb[q + 3] = ex + v0 + v1 + v2;
    __syncthreads();
    for (int t = tid; t < 1024; t += 256) h[t] = 0;     // reuse as rank cursors
    __syncthreads();
    unsigned mask = (1u << shift) - 1u;
    int cnt4 = cnt >> 2;
    const int4* keys4 = (const int4*)(keys + beg);
    const int4* vals4 = (const int4*)(vals + beg);
    const float4* w4 = (const float4*)(w + beg);
    for (int i = tid; i < cnt4; i += 256) {
        int4 k = keys4[i];
        int4 v = vals4[i];
        float4 ww = w4[i];
        {
            unsigned bkt = (unsigned)k.x >> shift;
            unsigned r = atomicAdd(&h[bkt], 1u);
            stage[lb[bkt] + r] = make_int2(__float_as_int(ww.x),
                                           (v.x << shift) | (unsigned)(k.x & (int)mask));
        }
        {
            unsigned bkt = (unsigned)k.y >> shift;
            unsigned r = atomicAdd(&h[bkt], 1u);
            stage[lb[bkt] + r] = make_int2(__float_as_int(ww.y),
                                           (v.y << shift) | (unsigned)(k.y & (int)mask));
        }
        {
            unsigned bkt = (unsigned)k.z >> shift;
            unsigned r = atomicAdd(&h[bkt], 1u);
            stage[lb[bkt] + r] = make_int2(__float_as_int(ww.z),
                                           (v.z << shift) | (unsigned)(k.z & (int)mask));
        }
        {
            unsigned bkt = (unsigned)k.w >> shift;
            unsigned r = atomicAdd(&h[bkt], 1u);
            stage[lb[bkt] + r] = make_int2(__float_as_int(ww.w),
                                           (v.w << shift) | (unsigned)(k.w & (int)mask));
        }
    }
    for (int i = cnt4 * 4 + tid; i < cnt; i += 256) {
        int k = keys[beg + i];
        unsigned bkt = (unsigned)k >> shift;
        unsigned r = atomicAdd(&h[bkt], 1u);
        stage[lb[bkt] + r] = make_int2(__float_as_int(w[beg + i]),
                                       (vals[beg + i] << shift) | (unsigned)(k & (int)mask));
    }
    __syncthreads();
    for (int i = tid; i < cnt; i += 256) {
        unsigned bb = 0;
#pragma unroll
        for (int step = 512; step > 0; step >>= 1) {
            unsigned cand = bb + step;
            if (cand < 1024 && lb[cand] <= (unsigned)i) bb = cand;
        }
        bucketed[gb[bb] + ((unsigned)i - lb[bb])] = stage[i];
    }
}

// per-bucket low-bit histogram -> per-node degree (generic, for C direction)
__global__ __launch_bounds__(256) void kDeg(const int2* __restrict__ bucketed,
                                            const unsigned* __restrict__ scanned,
                                            unsigned* __restrict__ deg,
                                            int nnodes, int nblk, int lowbits) {
    __shared__ unsigned h[1024];
    int d = blockIdx.x, tid = threadIdx.x;
    int W = 1 << lowbits;
    unsigned mask = (unsigned)(W - 1);
    unsigned base = scanned[(size_t)d * nblk], next = scanned[(size_t)(d + 1) * nblk];
    for (int t = tid; t < W; t += 256) h[t] = 0;
    __syncthreads();
    for (unsigned i = base + tid; i < next; i += 256)
        atomicAdd(&h[(unsigned)bucketed[i].y & mask], 1u);
    __syncthreads();
    int lo = d << lowbits;
    for (int t = tid; t < W; t += 256) {
        int node = lo + t;
        if (node < nnodes) deg[node] = h[t];
    }
}

// V direction: degree + fused pack of (c, x, rsqrt(deg)) in one pass
__global__ __launch_bounds__(256) void kDegPackV(const int2* __restrict__ bucketed,
                                                 const unsigned* __restrict__ scanned,
                                                 const float* __restrict__ var_c,
                                                 const float* __restrict__ var_x,
                                                 unsigned* __restrict__ deg,
                                                 float4* __restrict__ vcr,
                                                 int nnodes, int nblk) {
    __shared__ unsigned h[1024];
    int d = blockIdx.x, tid = threadIdx.x;
    unsigned base = scanned[(size_t)d * nblk], next = scanned[(size_t)(d + 1) * nblk];
    for (int t = tid; t < 1024; t += 256) h[t] = 0;
    __syncthreads();
    for (unsigned i = base + tid; i < next; i += 256)
        atomicAdd(&h[(unsigned)bucketed[i].y & 1023u], 1u);
    __syncthreads();
    int lo = d << 10;
    for (int t = tid; t < 1024; t += 256) {
        int node = lo + t;
        if (node < nnodes) {
            unsigned dg = h[t];
            deg[node] = dg;
            float rs = rsqrtf(fmaxf((float)dg, 1.0f));
            vcr[node] = make_float4(var_c[node], var_x[node], rs, 0.0f);
        }
    }
}

// NOTE: no __restrict__ -- used in-place (in == out) for the deg->start scans
__global__ __launch_bounds__(256) void k_scan_blocks(const unsigned int* in,
                                                     unsigned int* out,
                                                     unsigned int* bsum,
                                                     int n) {
    __shared__ unsigned int sT[256];
    int base = blockIdx.x * 1024 + threadIdx.x * 4;
    unsigned int v0 = 0, v1 = 0, v2 = 0, v3 = 0;
    if (base + 3 < n) {
        uint4 u = *(const uint4*)(in + base);
        v0 = u.x; v1 = u.y; v2 = u.z; v3 = u.w;
    } else {
        if (base     < n) v0 = in[base];
        if (base + 1 < n) v1 = in[base + 1];
        if (base + 2 < n) v2 = in[base + 2];
        if (base + 3 < n) v3 = in[base + 3];
    }
    sT[threadIdx.x] = v0 + v1 + v2 + v3;
    __syncthreads();
    for (int d = 1; d < 256; d <<= 1) {
        unsigned int add = (threadIdx.x >= (unsigned)d) ? sT[threadIdx.x - d] : 0u;
        __syncthreads();
        sT[threadIdx.x] += add;
        __syncthreads();
    }
    unsigned int excl = (threadIdx.x == 0) ? 0u : sT[threadIdx.x - 1];
    if (base     < n) out[base]     = excl;
    if (base + 1 < n) out[base + 1] = excl + v0;
    if (base + 2 < n) out[base + 2] = excl + v0 + v1;
    if (base + 3 < n) out[base + 3] = excl + v0 + v1 + v2;
    if (threadIdx.x == 255 && bsum) bsum[blockIdx.x] = sT[255];
}

// single-block looped exclusive scan (any n)
__global__ __launch_bounds__(256) void k_scan_mid(const unsigned* __restrict__ in,
                                                  unsigned* __restrict__ out, int n) {
    __shared__ unsigned sT[256];
    __shared__ unsigned carry;
    if (threadIdx.x == 0) carry = 0;
    __syncthreads();
    for (int base = 0; base < n; base += 256) {
        int i = base + threadIdx.x;
        unsigned v = (i < n) ? in[i] : 0u;
        sT[threadIdx.x] = v;
        __syncthreads();
        for (int d = 1; d < 256; d <<= 1) {
            unsigned add = (threadIdx.x >= (unsigned)d) ? sT[threadIdx.x - d] : 0u;
            __syncthreads();
            sT[threadIdx.x] += add;
            __syncthreads();
        }
        unsigned excl = carry + ((threadIdx.x == 0) ? 0u : sT[threadIdx.x - 1]);
        if (i < n) out[i] = excl;
        __syncthreads();
        if (threadIdx.x == 255) carry += sT[255];
        __syncthreads();
    }
}

__global__ __launch_bounds__(256) void k_scan_add(unsigned int* __restrict__ data,
                                                  const unsigned int* __restrict__ bscan,
                                                  int n) {
    int base = blockIdx.x * 1024 + threadIdx.x * 4;
    unsigned int add = bscan[blockIdx.x];
    if (base + 3 < n) {
        uint4 u = *(const uint4*)(data + base);
        u.x += add; u.y += add; u.z += add; u.w += add;
        *(uint4*)(data + base) = u;
    } else {
        if (base     < n) data[base]     += add;
        if (base + 1 < n) data[base + 1] += add;
        if (base + 2 < n) data[base + 2] += add;
        if (base + 3 < n) data[base + 3] += add;
    }
}

// ============================================================================
// Node pipeline
// ============================================================================

#define EMBADD(e)                                                             \
    {                                                                         \
        float4 vv = vcr[(size_t)(e).y];                                       \
        float we = __int_as_float((e).x);                                     \
        float t0 = fmaf(vv.x, wv0[0], fmaf(vv.y, wv1[0], bvr[0]));            \
        float t1 = fmaf(vv.x, wv0[1], fmaf(vv.y, wv1[1], bvr[1]));            \
        float t2 = fmaf(vv.x, wv0[2], fmaf(vv.y, wv1[2], bvr[2]));            \
        float t3 = fmaf(vv.x, wv0[3], fmaf(vv.y, wv1[3], bvr[3]));            \
        acc.x = fmaf(we, fmaxf(t0, 0.f) * vv.z, acc.x);                       \
        acc.y = fmaf(we, fmaxf(t1, 0.f) * vv.z, acc.y);                       \
        acc.z = fmaf(we, fmaxf(t2, 0.f) * vv.z, acc.z);                       \
        acc.w = fmaf(we, fmaxf(t3, 0.f) * vv.z, acc.w);                       \
    }

#define EMB4(eA, eB, eC, eD)                                                  \
    {                                                                         \
        float4 vA = vcr[(size_t)(eA).y];                                      \
        float4 vB = vcr[(size_t)(eB).y];                                      \
        float4 vC = vcr[(size_t)(eC).y];                                      \
        float4 vD = vcr[(size_t)(eD).y];                                      \
        float wA = __int_as_float((eA).x), wB = __int_as_float((eB).x);       \
        float wC = __int_as_float((eC).x), wD = __int_as_float((eD).x);       \
        float t0, t1, t2, t3;                                                 \
        t0 = fmaf(vA.x, wv0[0], fmaf(vA.y, wv1[0], bvr[0]));                  \
        t1 = fmaf(vA.x, wv0[1], fmaf(vA.y, wv1[1], bvr[1]));                  \
        t2 = fmaf(vA.x, wv0[2], fmaf(vA.y, wv1[2], bvr[2]));                  \
        t3 = fmaf(vA.x, wv0[3], fmaf(vA.y, wv1[3], bvr[3]));                  \
        acc.x = fmaf(wA, fmaxf(t0, 0.f) * vA.z, acc.x);                       \
        acc.y = fmaf(wA, fmaxf(t1, 0.f) * vA.z, acc.y);                       \
        acc.z = fmaf(wA, fmaxf(t2, 0.f) * vA.z, acc.z);                       \
        acc.w = fmaf(wA, fmaxf(t3, 0.f) * vA.z, acc.w);                       \
        t0 = fmaf(vB.x, wv0[0], fmaf(vB.y, wv1[0], bvr[0]));                  \
        t1 = fmaf(vB.x, wv0[1], fmaf(vB.y, wv1[1], bvr[1]));                  \
        t2 = fmaf(vB.x, wv0[2], fmaf(vB.y, wv1[2], bvr[2]));                  \
        t3 = fmaf(vB.x, wv0[3], fmaf(vB.y, wv1[3], bvr[3]));                  \
        acc.x = fmaf(wB, fmaxf(t0, 0.f) * vB.z, acc.x);                       \
        acc.y = fmaf(wB, fmaxf(t1, 0.f) * vB.z, acc.y);                       \
        acc.z = fmaf(wB, fmaxf(t2, 0.f) * vB.z, acc.z);                       \
        acc.w = fmaf(wB, fmaxf(t3, 0.f) * vB.z, acc.w);                       \
        t0 = fmaf(vC.x, wv0[0], fmaf(vC.y, wv1[0], bvr[0]));                  \
        t1 = fmaf(vC.x, wv0[1], fmaf(vC.y, wv1[1], bvr[1]));                  \
        t2 = fmaf(vC.x, wv0[2], fmaf(vC.y, wv1[2], bvr[2]));                  \
        t3 = fmaf(vC.x, wv0[3], fmaf(vC.y, wv1[3], bvr[3]));                  \
        acc.x = fmaf(wC, fmaxf(t0, 0.f) * vC.z, acc.x);                       \
        acc.y = fmaf(wC, fmaxf(t1, 0.f) * vC.z, acc.y);                       \
        acc.z = fmaf(wC, fmaxf(t2, 0.f) * vC.z, acc.z);                       \
        acc.w = fmaf(wC, fmaxf(t3, 0.f) * vC.z, acc.w);                       \
        t0 = fmaf(vD.x, wv0[0], fmaf(vD.y, wv1[0], bvr[0]));                  \
        t1 = fmaf(vD.x, wv0[1], fmaf(vD.y, wv1[1], bvr[1]));                  \
        t2 = fmaf(vD.x, wv0[2], fmaf(vD.y, wv1[2], bvr[2]));                  \
        t3 = fmaf(vD.x, wv0[3], fmaf(vD.y, wv1[3], bvr[3]));                  \
        acc.x = fmaf(wD, fmaxf(t0, 0.f) * vD.z, acc.x);                       \
        acc.y = fmaf(wD, fmaxf(t1, 0.f) * vD.z, acc.y);                       \
        acc.z = fmaf(wD, fmaxf(t2, 0.f) * vD.z, acc.z);                       \
        acc.w = fmaf(wD, fmaxf(t3, 0.f) * vD.z, acc.w);                       \
    }

// conv1 fused, half-bucket of 256 con nodes; on-the-fly var embedding from vcr
__global__ __launch_bounds__(512) void kF_con(const int2* __restrict__ bucketed,
                                              const unsigned* __restrict__ scanned,
                                              const unsigned* __restrict__ startC,
                                              const float4* __restrict__ vcr,
                                              const float* __restrict__ Wv,
                                              const float* __restrict__ bv,
                                              const float* __restrict__ W2,
                                              const float* __restrict__ b2,
                                              float* __restrict__ hs, int nblk, int netot) {
    __shared__ unsigned sraw[257], cr[256];
    __shared__ float sWv[20], sbv[10], sW[100], sb[10];
    __shared__ int2 stage[FCAP];
    int tid = threadIdx.x;
    int d = blockIdx.x >> 1, half = blockIdx.x & 1;
    int gbase = (d << 9) + half * 256;
    for (int t = tid; t < 100; t += 512) sW[t] = W2[t];
    if (tid < 10) sb[tid] = b2[tid];
    if (tid < 20) sWv[tid] = Wv[tid];
    if (tid >= 20 && tid < 30) sbv[tid - 20] = bv[tid - 20];
    for (int t = tid; t < 257; t += 512) {
        int g = gbase + t;
        sraw[t] = (g < NCON) ? startC[g] : (unsigned)netot;
    }
    if (tid < 256) cr[tid] = 0;
    __syncthreads();
    unsigned own_beg = sraw[0], own_end = sraw[256];
    bool fit = (int)(own_end - own_beg) <= FCAP;
    unsigned bbase = scanned[(size_t)d * nblk];
    unsigned bnext = scanned[(size_t)(d + 1) * nblk];
    int bsz = (int)(bnext - bbase);
    if (fit) {
        for (int i = tid; i < bsz; i += 512) {
            int2 p = bucketed[bbase + i];
            unsigned low = (unsigned)p.y & 511u;
            if ((int)(low >> 8) == half) {
                unsigned nl = low & 255u;
                unsigned r = atomicAdd(&cr[nl], 1u);
                stage[sraw[nl] - own_beg + r] = make_int2(p.x, p.y >> 9);
            }
        }
    }
    __syncthreads();
    int quad = tid >> 2, lane = tid & 3, c0 = lane * 4;
    float wv0[4], wv1[4], bvr[4];
#pragma unroll
    for (int k = 0; k < 4; k++) {
        int j = c0 + k;
        wv0[k] = (j < 10) ? sWv[j] : 0.f;
        wv1[k] = (j < 10) ? sWv[10 + j] : 0.f;
        bvr[k] = (j < 10) ? sbv[j] : 0.f;
    }
#pragma unroll
    for (int rr = 0; rr < 2; rr++) {
        int nl = rr * 128 + quad;
        int g = gbase + nl;
        if (g >= NCON) continue;
        float4 acc = make_float4(0.f, 0.f, 0.f, 0.f);
        unsigned cnt;
        if (fit) {
            unsigned beg = sraw[nl] - own_beg;
            cnt = cr[nl];
            unsigned end = beg + cnt, p = beg;
            for (; p + 4 <= end; p += 4) {
                int2 e0 = stage[p], e1 = stage[p + 1], e2 = stage[p + 2], e3 = stage[p + 3];
                EMB4(e0, e1, e2, e3);
            }
            for (; p < end; ++p) {
                int2 e = stage[p];
                EMBADD(e);
            }
        } else {   // statistically unreachable safety path
            cnt = 0;
            unsigned target = (unsigned)(half * 256 + nl);
            for (int i = 0; i < bsz; ++i) {
                int2 p = bucketed[bbase + i];
                if (((unsigned)p.y & 511u) == target) {
                    ++cnt;
                    int2 e = make_int2(p.x, p.y >> 9);
                    EMBADD(e);
                }
            }
        }
        float rs = rsqrtf(fmaxf((float)cnt, 1.0f));
        float a[10];
        a[0] = __shfl(acc.x, 0, 4); a[1] = __shfl(acc.y, 0, 4);
        a[2] = __shfl(acc.z, 0, 4); a[3] = __shfl(acc.w, 0, 4);
        a[4] = __shfl(acc.x, 1, 4); a[5] = __shfl(acc.y, 1, 4);
        a[6] = __shfl(acc.z, 1, 4); a[7] = __shfl(acc.w, 1, 4);
        a[8] = __shfl(acc.x, 2, 4); a[9] = __shfl(acc.y, 2, 4);
#pragma unroll
        for (int j = 0; j < 10; j++) a[j] *= rs;
        float o[12];
#pragma unroll
        for (int k = 0; k < 10; k++) {
            float t = sb[k];
#pragma unroll
            for (int j = 0; j < 10; j++) t = fmaf(a[j], sW[j * 10 + k], t);
            o[k] = fmaxf(t, 0.0f) * rs;   // relu + prescale for conv2
        }
        o[10] = 0.0f; o[11] = 0.0f;
        float4 wv = (lane < 3) ? make_float4(o[c0], o[c0 + 1], o[c0 + 2], o[c0 + 3])
                               : make_float4(0.f, 0.f, 0.f, 0.f);
        *(float4*)(hs + (size_t)g * 16 + c0) = wv;
    }
}

#define GATHER4(eA, eB, eC, eD, TAB)                                          \
    {                                                                         \
        float4 v0 = *(const float4*)(TAB + (size_t)(eA).y * 16 + c0);         \
        float4 v1 = *(const float4*)(TAB + (size_t)(eB).y * 16 + c0);         \
        float4 v2 = *(const float4*)(TAB + (size_t)(eC).y * 16 + c0);         \
        float4 v3 = *(const float4*)(TAB + (size_t)(eD).y * 16 + c0);         \
        float w0 = __int_as_float((eA).x), w1 = __int_as_float((eB).x);       \
        float w2 = __int_as_float((eC).x), w3 = __int_as_float((eD).x);       \
        acc.x = fmaf(w0, v0.x, acc.x); acc.y = fmaf(w0, v0.y, acc.y);         \
        acc.z = fmaf(w0, v0.z, acc.z); acc.w = fmaf(w0, v0.w, acc.w);         \
        acc.x = fmaf(w1, v1.x, acc.x); acc.y = fmaf(w1, v1.y, acc.y);         \
        acc.z = fmaf(w1, v1.z, acc.z); acc.w = fmaf(w1, v1.w, acc.w);         \
        acc.x = fmaf(w2, v2.x, acc.x); acc.y = fmaf(w2, v2.y, acc.y);         \
        acc.z = fmaf(w2, v2.z, acc.z); acc.w = fmaf(w2, v2.w, acc.w);         \
        acc.x = fmaf(w3, v3.x, acc.x); acc.y = fmaf(w3, v3.y, acc.y);         \
        acc.z = fmaf(w3, v3.z, acc.z); acc.w = fmaf(w3, v3.w, acc.w);         \
    }

// conv2 fused, half-bucket of 512 var nodes: rank-stage, gather hs, dense + MLP,
// per-block partial mean.
__global__ __launch_bounds__(512) void kF_fin(const int2* __restrict__ bucketed,
                                              const unsigned* __restrict__ scanned,
                                              const unsigned* __restrict__ startV,
                                              const float* __restrict__ feat,
                                              const float* __restrict__ W2,
                                              const float* __restrict__ b2,
                                              const float* __restrict__ Wo1,
                                              const float* __restrict__ bo1,
                                              const float* __restrict__ Wo2,
                                              const float* __restrict__ bo2,
                                              const float* __restrict__ Wo3,
                                              const float* __restrict__ bo3,
                                              double* __restrict__ partials, int nblk, int netot) {
    __shared__ unsigned sraw[513], cr[512];
    __shared__ float sW2[100], sb2[10], sWo1[100], sbo1[10], sWo2[100], sbo2[10], sWo3[10], sbo3v;
    __shared__ int2 stage[FCAP];
    __shared__ double red[512];
    int tid = threadIdx.x;
    int d = blockIdx.x >> 1, half = blockIdx.x & 1;
    int gbase = (d << 10) + half * 512;
    for (int t = tid; t < 100; t += 512) { sW2[t] = W2[t]; sWo1[t] = Wo1[t]; sWo2[t] = Wo2[t]; }
    if (tid < 10) {
        sb2[tid] = b2[tid]; sbo1[tid] = bo1[tid]; sbo2[tid] = bo2[tid]; sWo3[tid] = Wo3[tid];
    }
    if (tid == 0) sbo3v = bo3[0];
    for (int t = tid; t < 513; t += 512) {
        int g = gbase + t;
        sraw[t] = (g < NVAR) ? startV[g] : (unsigned)netot;
    }
    cr[tid] = 0;
    __syncthreads();
    unsigned own_beg = sraw[0], own_end = sraw[512];
    bool fit = (int)(own_end - own_beg) <= FCAP;
    unsigned bbase = scanned[(size_t)d * nblk];
    unsigned bnext = scanned[(size_t)(d + 1) * nblk];
    int bsz = (int)(bnext - bbase);
    if (fit) {
        for (int i = tid; i < bsz; i += 512) {
            int2 p = bucketed[bbase + i];
            unsigned low = (unsigned)p.y & 1023u;
            if ((int)(low >> 9) == half) {
                unsigned nl = low & 511u;
                unsigned r = atomicAdd(&cr[nl], 1u);
                stage[sraw[nl] - own_beg + r] = make_int2(p.x, p.y >> 10);
            }
        }
    }
    __syncthreads();
    int quad = tid >> 2, lane = tid & 3, c0 = lane * 4;
    double accd = 0.0;
#pragma unroll
    for (int rr = 0; rr < 4; rr++) {
        int nl = rr * 128 + quad;
        int g = gbase + nl;
        if (g >= NVAR) continue;
        float4 acc = make_float4(0.f, 0.f, 0.f, 0.f);
        unsigned cnt;
        if (fit) {
            unsigned beg = sraw[nl] - own_beg;
            cnt = cr[nl];
            unsigned end = beg + cnt, p = beg;
            for (; p + 4 <= end; p += 4) {
                int2 e0 = stage[p], e1 = stage[p + 1], e2 = stage[p + 2], e3 = stage[p + 3];
                GATHER4(e0, e1, e2, e3, feat);
            }
            for (; p < end; ++p) {
                int2 e = stage[p];
                float4 v = *(const float4*)(feat + (size_t)e.y * 16 + c0);
                float we = __int_as_float(e.x);
                acc.x = fmaf(we, v.x, acc.x); acc.y = fmaf(we, v.y, acc.y);
                acc.z = fmaf(we, v.z, acc.z); acc.w = fmaf(we, v.w, acc.w);
            }
        } else {   // statistically unreachable safety path
            cnt = 0;
            unsigned target = (unsigned)(half * 512 + nl);
            for (int i = 0; i < bsz; ++i) {
                int2 p = bucketed[bbase + i];
                if (((unsigned)p.y & 1023u) == target) {
                    ++cnt;
                    float4 v = *(const float4*)(feat + (size_t)((unsigned)p.y >> 10) * 16 + c0);
                    float we = __int_as_float(p.x);
                    acc.x = fmaf(we, v.x, acc.x); acc.y = fmaf(we, v.y, acc.y);
                    acc.z = fmaf(we, v.z, acc.z); acc.w = fmaf(we, v.w, acc.w);
                }
            }
        }
        float rs = rsqrtf(fmaxf((float)cnt, 1.0f));
        float a[10];
        a[0] = __shfl(acc.x, 0, 4); a[1] = __shfl(acc.y, 0, 4);
        a[2] = __shfl(acc.z, 0, 4); a[3] = __shfl(acc.w, 0, 4);
        a[4] = __shfl(acc.x, 1, 4); a[5] = __shfl(acc.y, 1, 4);
        a[6] = __shfl(acc.z, 1, 4); a[7] = __shfl(acc.w, 1, 4);
        a[8] = __shfl(acc.x, 2, 4); a[9] = __shfl(acc.y, 2, 4);
#pragma unroll
        for (int j = 0; j < 10; j++) a[j] *= rs;
        float hh[10], z[10];
#pragma unroll
        for (int k = 0; k < 10; k++) {
            float t = sb2[k];
#pragma unroll
            for (int j = 0; j < 10; j++) t = fmaf(a[j], sW2[j * 10 + k], t);
            hh[k] = fmaxf(t, 0.0f);
        }
#pragma unroll
        for (int k = 0; k < 10; k++) {
            float t = sbo1[k];
#pragma unroll
            for (int j = 0; j < 10; j++) t = fmaf(hh[j], sWo1[j * 10 + k], t);
            z[k] = fmaxf(t, 0.0f);
        }
        float t3 = sbo3v;
#pragma unroll
        for (int k = 0; k < 10; k++) {
            float t = sbo2[k];
#pragma unroll
            for (int j = 0; j < 10; j++) t = fmaf(z[j], sWo2[j * 10 + k], t);
            t = fmaxf(t, 0.0f);
            t3 = fmaf(t, sWo3[k], t3);
        }
        if (lane == 0) accd += (double)t3;
    }
    red[tid] = accd;
    __syncthreads();
    for (int off = 256; off > 0; off >>= 1) {
        if (tid < off) red[tid] += red[tid + off];
        __syncthreads();
    }
    if (tid == 0) partials[blockIdx.x] = red[0];
}

__global__ __launch_bounds__(256) void k_out(const double* __restrict__ partials, int np,
                                             float* __restrict__ out) {
    __shared__ double red[256];
    double a = 0.0;
    for (int i = threadIdx.x; i < np; i += blockDim.x) a += partials[i];
    red[threadIdx.x] = a;
    __syncthreads();
    for (int off = 128; off > 0; off >>= 1) {
        if (threadIdx.x < off) red[threadIdx.x] += red[threadIdx.x + off];
        __syncthreads();
    }
    if (threadIdx.x == 0) out[0] = (float)(red[0] / (double)NVAR);
}

// ============================================================================
// Launch
// ============================================================================

extern "C" void kernel_launch(void* const* d_in, const int* in_sizes, int n_in,
                              void* d_out, int out_size, void* d_ws, size_t ws_size,
                              hipStream_t stream) {
    const float* var_c  = (const float*)d_in[0];
    const float* var_x  = (const float*)d_in[1];
    const int*   e_src  = (const int*)d_in[3];
    const int*   e_dst  = (const int*)d_in[4];
    const float* e_w    = (const float*)d_in[5];
    const float* Wv     = (const float*)d_in[6];
    const float* bv     = (const float*)d_in[7];
    const float* W2     = (const float*)d_in[12];
    const float* b2     = (const float*)d_in[13];
    const float* Wo1    = (const float*)d_in[14];
    const float* bo1    = (const float*)d_in[15];
    const float* Wo2    = (const float*)d_in[16];
    const float* bo2    = (const float*)d_in[17];
    const float* Wo3    = (const float*)d_in[18];
    const float* bo3    = (const float*)d_in[19];
    float* out = (float*)d_out;
    const int ne = in_sizes[3];
    (void)n_in; (void)out_size; (void)ws_size;

    const int B = 256;
    const int nblkA = (ne + EPB - 1) / EPB;       // 977
    const int scanN = 1024 * nblkA;               // ~1.0M
    const int NBs   = (scanN + 1023) / 1024;      // 977
    const int BKV   = (NVAR + 1023) >> 10;        // 977 (shift 10)
    const int BKC   = (NCON + 511) >> 9;          // 977 (shift 9)
    const int NBV   = (NVAR + 1023) / 1024;       // 977
    const int NBC   = (NCON + 1023) / 1024;       // 489
    const int ne4   = ne / 4;

    char* ws = (char*)d_ws;
    size_t off = 0;
    auto walloc = [&](size_t bytes) {
        void* p = ws + off;
        off = (off + bytes + 255) & ~(size_t)255;
        return p;
    };

    int2*     bucketedV = (int2*)walloc((size_t)ne * 8);           // 64 MB
    int2*     bucketedC = (int2*)walloc((size_t)ne * 8);           // 64 MB
    float4*   vcr       = (float4*)walloc((size_t)NVAR * 16);      // 16 MB
    float*    hs64      = (float*)walloc((size_t)NCON * 16 * 4);   // 32 MB
    unsigned* scannedV  = (unsigned*)walloc((size_t)scanN * 4);    //  4 MB
    unsigned* scannedC  = (unsigned*)walloc((size_t)scanN * 4);    //  4 MB
    unsigned* bhV       = (unsigned*)walloc((size_t)scanN * 4);    //  4 MB (bucket-major)
    unsigned* bhC       = (unsigned*)walloc((size_t)scanN * 4);    //  4 MB (bucket-major)
    unsigned* bhTV      = (unsigned*)walloc((size_t)scanN * 4);    //  4 MB (block-major)
    unsigned* bhTC      = (unsigned*)walloc((size_t)scanN * 4);    //  4 MB (block-major)
    unsigned* bsumA     = (unsigned*)walloc(8192);
    unsigned* bscanA    = (unsigned*)walloc(8192);
    double*   partials  = (double*)walloc((size_t)(BKV * 2) * 8 + 64);
    // overlays: bhV dead after its bucket scan -> deg_var (in-place scan -> startV)
    //           bhC dead after its bucket scan -> deg_con (in-place scan -> startC)
    unsigned* deg_var   = bhV;
    unsigned* deg_con   = bhC;

    // 1. fused dual histogram (block-major, coalesced writes)
    kA_hist2<<<nblkA, B, 0, stream>>>((const int4*)e_src, (const int4*)e_dst,
                                      bhTV, bhTC, ne4);

    // 2. transpose to bucket-major for the scans
    dim3 tgrid(1024 / 32, (nblkA + 31) / 32);
    k_transpose<<<tgrid, B, 0, stream>>>(bhTV, bhV, nblkA);
    k_transpose<<<tgrid, B, 0, stream>>>(bhTC, bhC, nblkA);

    // 3. bucket-level scans -> global segment bases
    k_scan_blocks<<<NBs, B, 0, stream>>>(bhV, scannedV, bsumA, scanN);
    k_scan_mid   <<<1,   B, 0, stream>>>(bsumA, bscanA, NBs);
    k_scan_add   <<<NBs, B, 0, stream>>>(scannedV, bscanA, scanN);
    k_scan_blocks<<<NBs, B, 0, stream>>>(bhC, scannedC, bsumA, scanN);
    k_scan_mid   <<<1,   B, 0, stream>>>(bsumA, bscanA, NBs);
    k_scan_add   <<<NBs, B, 0, stream>>>(scannedC, bscanA, scanN);

    // 4. V-direction bucketing (histogram loaded from bhTV); bhV now dead
    kA_scat<<<nblkA, B, 0, stream>>>(e_src, e_dst, e_w, bhTV, scannedV, bucketedV,
                                     ne, 10, nblkA);

    // 5. per-node var degrees + fused (c,x,rsqrt) pack (overlay on bhV)
    kDegPackV<<<BKV, B, 0, stream>>>(bucketedV, scannedV, var_c, var_x,
                                     deg_var, vcr, NVAR, nblkA);

    // 6. in-place exclusive scan deg_var -> startV
    k_scan_blocks<<<NBV, B, 0, stream>>>(deg_var, deg_var, bsumA, NVAR);
    k_scan_mid   <<<1,   B, 0, stream>>>(bsumA, bscanA, NBV);
    k_scan_add   <<<NBV, B, 0, stream>>>(deg_var, bscanA, NVAR);

    // 7. C-direction bucketing (histogram loaded from bhTC); bhC now dead
    kA_scat<<<nblkA, B, 0, stream>>>(e_dst, e_src, e_w, bhTC, scannedC, bucketedC,
                                     ne, 9, nblkA);

    // 8. per-node con degrees (overlay on bhC), in-place scan -> startC
    kDeg<<<BKC, B, 0, stream>>>(bucketedC, scannedC, deg_con, NCON, nblkA, 9);
    k_scan_blocks<<<NBC, B, 0, stream>>>(deg_con, deg_con, bsumA, NCON);
    k_scan_mid   <<<1,   B, 0, stream>>>(bsumA, bscanA, NBC);
    k_scan_add   <<<NBC, B, 0, stream>>>(deg_con, bscanA, NCON);

    // 9. conv1 fused (half-buckets, on-the-fly embedding from vcr)
    kF_con<<<BKC * 2, 512, 0, stream>>>(bucketedC, scannedC, deg_con, vcr, Wv, bv,
                                        W2, b2, hs64, nblkA, ne);

    // 10. conv2 fused (half-buckets) + MLP + partials
    kF_fin<<<BKV * 2, 512, 0, stream>>>(bucketedV, scannedV, deg_var, hs64, W2, b2,
                                        Wo1, bo1, Wo2, bo2, Wo3, bo3, partials, nblkA, ne);

    // 11. final mean
    k_out<<<1, B, 0, stream>>>(partials, BKV * 2, out);
}